// Round 9
// baseline (272.760 us; speedup 1.0000x reference)
//
#include <hip/hip_runtime.h>

typedef unsigned short ushort_t;
typedef unsigned long long ull_t;
typedef __attribute__((ext_vector_type(8))) short bf16x8;
typedef __attribute__((ext_vector_type(4))) float f32x4;

static __device__ __forceinline__ unsigned short f2bf(float f) {
  unsigned u = __float_as_uint(f);
  u = (u + 0x7FFFu + ((u >> 16) & 1u)) >> 16;
  return (unsigned short)u;
}

static __device__ __forceinline__ f32x4 max4(f32x4 a, f32x4 b) {
  f32x4 r;
  r[0] = fmaxf(a[0], b[0]); r[1] = fmaxf(a[1], b[1]);
  r[2] = fmaxf(a[2], b[2]); r[3] = fmaxf(a[3], b[3]);
  return r;
}

// Single-use hierarchical grid barrier, one state block per barrier id.
// R7/R8 measured: barrier design moves the tail <2us — kept for safety
// (single-use => no reset races; arrive-only supported). nb = arrivals
// (multiple of 8); leaf threshold = nb/8.
// Layout per barrier: leaf[i]@i*32 (i<8), root@256, gen[i]@288+i*32.
static __device__ __forceinline__ void gbar(int* bar0, int bid, int nb,
                                            bool do_wait) {
  __syncthreads();
  if (threadIdx.x == 0) {
    int* bar = bar0 + (bid << 10);
    __threadfence();                        // release
    const int leaf = (blockIdx.x & 7) << 5;
    const int nleaf = nb >> 3;
    if (__hip_atomic_fetch_add(&bar[leaf], 1, __ATOMIC_ACQ_REL,
                               __HIP_MEMORY_SCOPE_AGENT) == nleaf - 1) {
      if (__hip_atomic_fetch_add(&bar[256], 1, __ATOMIC_ACQ_REL,
                                 __HIP_MEMORY_SCOPE_AGENT) == 7) {
#pragma unroll
        for (int i = 0; i < 8; ++i)
          __hip_atomic_store(&bar[288 + (i << 5)], 1, __ATOMIC_RELEASE,
                             __HIP_MEMORY_SCOPE_AGENT);
      }
    }
    if (do_wait) {
      int* mygen = &bar[288 + leaf];
      for (int it = 0; it < (1 << 22); ++it) {
        if (__hip_atomic_load(mygen, __ATOMIC_RELAXED,
                              __HIP_MEMORY_SCOPE_AGENT) != 0) break;
        __builtin_amdgcn_s_sleep(2);
      }
      __threadfence();                      // acquire
    }
  }
  __syncthreads();
}

// ---------------------------------------------------------------------------
// Workspace layout (fp32-element offsets):
//   h1    @ 0          : 16777216 ushorts (dead after conv2; spw/shw reuse it)
//     spw @ 2621440    : 1024 floats (chunk-max output)
//     shw @ 2622464    : 2048 floats (fc1 output)
//   w2f   @ 8388608    : 14336 ushorts (conv2 weight frags)
//   wg1Tb @ 8395776    : 1024x2048 ushorts
//   wg2Tb @ 9444352    : 512x1024 ushorts
//   wg3Tb @ 9706496    : 256x512 ushorts
//   featb @ 9772032    : 256x2048 ushorts
//   g1b   @ 10034176   : 256x1024 ushorts
//   g2b   @ 10165248   : 256x512 ushorts
//   c2b   @ 16777216   : 4194304 ushorts bf16 (ALIASED: xb16, consumed pre-conv2)
//   An    @ 21495808   : 4*64*64
//   bar   @ 22364160   : 5120 ints (5 single-use barrier states x 1024)
// ---------------------------------------------------------------------------

// ---------------- fused prep: x2bf | w2f | 3x transpose | gcn_norm ---------
__device__ __forceinline__ void prep_transpose(
    const float* __restrict__ W, ushort_t* __restrict__ out,
    int K, int N, int n0, int k0, int t, float (*tile)[33])
{
  const int tx = t & 31, ty = t >> 5;
#pragma unroll
  for (int i = 0; i < 4; ++i) {
    const int k = k0 + ty + i * 8;
    tile[ty + i * 8][tx] = W[(size_t)k * N + n0 + tx];
  }
  __syncthreads();
#pragma unroll
  for (int i = 0; i < 4; ++i) {
    const int n = n0 + ty + i * 8;
    out[(size_t)n * K + k0 + tx] = f2bf(tile[tx][ty + i * 8]);
  }
}

__global__ __launch_bounds__(256) void k_prep(
    const float* __restrict__ x, ushort_t* __restrict__ xb16,
    const float* __restrict__ w2, ushort_t* __restrict__ w2f,
    const float* __restrict__ wg1, ushort_t* __restrict__ wg1T,
    const float* __restrict__ wg2, ushort_t* __restrict__ wg2T,
    const float* __restrict__ wg3, ushort_t* __restrict__ wg3T,
    const int* __restrict__ adj, float* __restrict__ An)
{
  __shared__ float tile[32][33];
  __shared__ float dinv[64];
  __shared__ int part[256];
  int b = blockIdx.x;
  const int t = threadIdx.x;
  if (b < 8192) {                       // x -> bf16
    const int tid = b * 256 + t;
    const float4 v = ((const float4*)x)[tid];
    const unsigned lo = (unsigned)f2bf(v.x) | ((unsigned)f2bf(v.y) << 16);
    const unsigned hi = (unsigned)f2bf(v.z) | ((unsigned)f2bf(v.w) << 16);
    ((uint2*)xb16)[tid] = make_uint2(lo, hi);
    return;
  }
  b -= 8192;
  if (b < 56) {                         // conv2 weight frags
    const int tid = b * 256 + t;
    if (tid < 14336) {
      const int nt = tid / 7168, rem = tid % 7168;
      const int kk = rem / 512, rem2 = rem % 512;
      const int l = rem2 >> 3, j = rem2 & 7;
      const int n = nt * 16 + (l & 15);
      const int k = (l >> 4) * 8 + kk * 32 + j;
      float v = 0.f;
      if (k < 432) v = w2[n * 432 + k];
      w2f[tid] = f2bf(v);
    }
    return;
  }
  b -= 56;
  if (b < 2048) { prep_transpose(wg1, wg1T, 2048, 1024, (b & 31) << 5, (b >> 5) << 5, t, tile); return; }
  b -= 2048;
  if (b < 512)  { prep_transpose(wg2, wg2T, 1024, 512,  (b & 15) << 5, (b >> 4) << 5, t, tile); return; }
  b -= 512;
  if (b < 128)  { prep_transpose(wg3, wg3T, 512,  256,  (b & 7)  << 5, (b >> 3) << 5, t, tile); return; }
  b -= 128;
  {                                     // gcn_norm, b in [0,4)
    const int i = t >> 2, q = t & 3;
    const int* ab = adj + b * 4096 + i * 64 + q * 16;
    int d = 0;
#pragma unroll
    for (int j = 0; j < 16; ++j) d += (ab[j] != 0) ? 1 : 0;
    part[t] = d;
    __syncthreads();
    if (q == 0)
      dinv[i] = rsqrtf((float)(1 + part[t] + part[t + 1] + part[t + 2] + part[t + 3]));
    __syncthreads();
    for (int idx = t; idx < 4096; idx += 256) {
      const int ii = idx >> 6, jj = idx & 63;
      const float a = (ii == jj) ? 1.f : ((adj[b * 4096 + idx] != 0) ? 1.f : 0.f);
      An[b * 4096 + idx] = a * dinv[ii] * dinv[jj];
    }
  }
}

// ---------------- K1: conv1 + maxpool3 as bf16 MFMA "pooled-direct" --------
// (R8 form — measured best; do not touch.)
__global__ __launch_bounds__(256) void k_conv1_mfma(
    const ushort_t* __restrict__ xb16, const float* __restrict__ wc,
    const float* __restrict__ bc, ushort_t* __restrict__ h1)
{
  __shared__ ushort_t L[2 * 34 * 76];
  char* Lb = (char*)L;
  const int bn = blockIdx.x >> 3, zg = blockIdx.x & 7;
  const int t = threadIdx.x;
  const int w = t >> 6, l = t & 63;
  const int grp = l >> 4, m = l & 15, ch = l & 15;
  const float NINF = -1e30f;

  union { short s[8]; bf16x8 v; } uA, uB;
#pragma unroll
  for (int j = 0; j < 8; ++j) {
    const int k = grp * 8 + j;
    float wA = 0.f, wB = 0.f;
    if (k < 12) {
      const int dx = k >> 2, dz = k & 3;
      if (dz < 3) { wA = wc[ch*27 + dz*9 + 0 + dx]; wB = wc[ch*27 + dz*9 + 6 + dx]; }
    } else if (k >= 16 && k < 28) {
      const int kk = k - 16, dx = kk >> 2, dz = kk & 3;
      if (dz < 3) wA = wc[ch*27 + dz*9 + 3 + dx];
    }
    uA.s[j] = (short)f2bf(wA);
    uB.s[j] = (short)f2bf(wB);
  }

  int aX1[3], aX2[3];
#pragma unroll
  for (int s = 0; s < 3; ++s) {
    const int Q1 = 2*m + s + 2*(grp & 1);
    const int Q2 = Q1 + 1;
    aX1[s] = (Q1 & 1) * 5168 + (Q1 >> 1) * 8;
    aX2[s] = (Q2 & 1) * 5168 + (Q2 >> 1) * 8;
  }
  const int rsel = (grp >> 1) * 152;

  for (int u = t; u < 200; u += 256) {
    int addr;
    if (u < 72) {
      const int rr = (u < 36) ? 0 : 33;
      const int s = (u < 36) ? u : u - 36;
      const int pp = s / 18, slot = s - pp * 18;
      addr = pp * 5168 + rr * 152 + slot * 8;
    } else {
      const int v = u - 72;
      const int rr = 1 + (v >> 2);
      const int pp = (v >> 1) & 1;
      const int slot = (v & 1) * 17;
      addr = pp * 5168 + rr * 152 + slot * 8;
    }
    *(ull_t*)(Lb + addr) = 0ull;
  }

  f32x4 accZ[4][2];
#pragma unroll
  for (int j = 0; j < 4; ++j)
#pragma unroll
    for (int p = 0; p < 2; ++p) accZ[j][p] = (f32x4){NINF, NINF, NINF, NINF};

  const ushort_t* xb = xb16 + (size_t)bn * 32768;

#pragma unroll 1
  for (int ci = 0; ci < 5; ++ci) {
    const int cz = 4*zg - 1 + ci;
    if (cz < 0) continue;
    if (t < 128) {
      const int r = 1 + (t >> 2), g = t & 3;
      const ushort_t* xrow = xb + (r - 1) * 32 + g * 8;
      uint4 u0 = make_uint4(0u, 0u, 0u, 0u), u2 = make_uint4(0u, 0u, 0u, 0u);
      if (cz > 0)  u0 = *(const uint4*)(xrow + (cz - 1) * 1024);
      const uint4 u1 = *(const uint4*)(xrow + cz * 1024);
      if (cz < 31) u2 = *(const uint4*)(xrow + (cz + 1) * 1024);
      char* b0 = Lb + r * 152 + (4 * g + 1) * 8;
      char* b1 = Lb + 5168 + r * 152 + (4 * g + 1) * 8;
      const unsigned* p0 = (const unsigned*)&u0;
      const unsigned* p1 = (const unsigned*)&u1;
      const unsigned* p2 = (const unsigned*)&u2;
#pragma unroll
      for (int e = 0; e < 4; ++e) {
        const unsigned w0 = p0[e], w1 = p1[e], w2v = p2[e];
        const unsigned lo_e = (w0 & 0xFFFFu) | (w1 << 16);
        const unsigned hi_e = (w2v & 0xFFFFu);
        const unsigned lo_o = (w0 >> 16) | (w1 & 0xFFFF0000u);
        const unsigned hi_o = (w2v >> 16);
        *(ull_t*)(b0 + e * 8) = (ull_t)lo_e | ((ull_t)hi_e << 32);
        *(ull_t*)(b1 + e * 8) = (ull_t)lo_o | ((ull_t)hi_o << 32);
      }
    }
    __syncthreads();
    f32x4 accP0 = (f32x4){NINF, NINF, NINF, NINF};
    f32x4 accP1 = (f32x4){NINF, NINF, NINF, NINF};
#pragma unroll
    for (int yy = 0; yy < 9; ++yy) {
      if (yy == 0 && w == 0) continue;
      const int y = 8 * w - 1 + yy;
      const int rbA = y * 152 + rsel;
      const int rbB = (y + 2) * 152;
      f32x4 Cy;
#pragma unroll
      for (int s = 0; s < 3; ++s) {
        union { ull_t u[2]; bf16x8 v; } fA, fB;
        fA.u[0] = *(const ull_t*)(Lb + aX1[s] + rbA);
        fA.u[1] = *(const ull_t*)(Lb + aX2[s] + rbA);
        fB.u[0] = *(const ull_t*)(Lb + aX1[s] + rbB);
        fB.u[1] = *(const ull_t*)(Lb + aX2[s] + rbB);
        f32x4 acc = (f32x4){0.f, 0.f, 0.f, 0.f};
        acc = __builtin_amdgcn_mfma_f32_16x16x32_bf16(fA.v, uA.v, acc, 0, 0, 0);
        acc = __builtin_amdgcn_mfma_f32_16x16x32_bf16(fB.v, uB.v, acc, 0, 0, 0);
        if (s == 0) acc[0] = (l < 16) ? NINF : acc[0];
        Cy = (s == 0) ? acc : max4(Cy, acc);
      }
      if (yy & 1) {
        const int c = (yy - 1) / 2;
        if ((c & 1) == 0) accP0 = max4(accP0, Cy); else accP1 = max4(accP1, Cy);
      } else {
        const int cl = yy / 2 - 1;
        const int chh = yy / 2;
        if (cl >= 0) {
          if ((cl & 1) == 0) {
            accP0 = max4(accP0, Cy);
            if (ci <= 2) accZ[cl][0] = max4(accZ[cl][0], accP0);
            if (ci >= 2) accZ[cl][1] = max4(accZ[cl][1], accP0);
            accP0 = (f32x4){NINF, NINF, NINF, NINF};
          } else {
            accP1 = max4(accP1, Cy);
            if (ci <= 2) accZ[cl][0] = max4(accZ[cl][0], accP1);
            if (ci >= 2) accZ[cl][1] = max4(accZ[cl][1], accP1);
            accP1 = (f32x4){NINF, NINF, NINF, NINF};
          }
        }
        if (chh <= 3) {
          if ((chh & 1) == 0) accP0 = max4(accP0, Cy); else accP1 = max4(accP1, Cy);
        }
      }
    }
    __syncthreads();
  }

  const float biasv = bc[ch];
#pragma unroll
  for (int j = 0; j < 4; ++j) {
    const int py = 4 * w + j;
#pragma unroll
    for (int p = 0; p < 2; ++p) {
      const int pz = 2 * zg + p;
      const f32x4 v = accZ[j][p];
      const unsigned lo = (unsigned)f2bf(fmaxf(v[0] + biasv, 0.f)) |
                          ((unsigned)f2bf(fmaxf(v[1] + biasv, 0.f)) << 16);
      const unsigned hi = (unsigned)f2bf(fmaxf(v[2] + biasv, 0.f)) |
                          ((unsigned)f2bf(fmaxf(v[3] + biasv, 0.f)) << 16);
      ushort_t* dst = h1 + (((size_t)(bn * 16 + ch) * 16 + pz) << 8) + py * 16 + grp * 4;
      *(uint2*)dst = make_uint2(lo, hi);
    }
  }
}

// ---------------- K2: conv2 MFMA implicit GEMM, LDS-staged input -----------
// R9: output stored as bf16 (halves conv2 write + pool read HBM traffic).
// Block 0 also zero-inits the 5 single-use grid-barrier states for k_tail.
__global__ __launch_bounds__(128) void k_conv2(
    const ushort_t* __restrict__ h1, const ushort_t* __restrict__ w2f,
    ushort_t* __restrict__ c2b, int* __restrict__ bar)
{
  __shared__ ushort_t U[16 * 456];            // 14592 B: Hs (11520 B) then As
  ushort_t* Hs = U;                           // Hs[row*20 + ix], row<288
  unsigned* Hsd = (unsigned*)U;               // dword view, stride 10
  ushort_t* As = U;                           // As[m*456 + k]
  const int b = blockIdx.x;
  const int bn = b >> 5, oz = (b >> 2) & 7, yg = b & 3;
  const int t = threadIdx.x;
  const ushort_t* hb = h1 + ((size_t)bn << 16);
  const int w = t >> 6, l = t & 63;

  if (b == 0) {
    for (int i = t; i < 5120; i += 128) bar[i] = 0;
  }

  bf16x8 bfr[14];
#pragma unroll
  for (int kk = 0; kk < 14; ++kk)
    bfr[kk] = *(const bf16x8*)(const void*)&w2f[(((w * 14) + kk) * 64 + l) * 8];

  // ---- stage Hs: 288 rows x 4 uint2-quads, coalesced, OOB -> 0 ----
#pragma unroll
  for (int it = 0; it < 9; ++it) {
    const int u = t + it * 128;               // 0..1151
    const int row = u >> 2, q = u & 3;
    const int ic = row / 18;
    const int r2 = row - ic * 18;
    const int izp = r2 / 6;
    const int iyp = r2 - izp * 6;
    const int iz = 2 * oz - 1 + izp;
    const int iy = 4 * yg - 1 + iyp;
    uint2 v = make_uint2(0u, 0u);
    if ((unsigned)iz < 16u && (unsigned)iy < 16u)
      v = *(const uint2*)(hb + (ic << 12) + (iz << 8) + (iy << 4) + q * 4);
    *(uint2*)&Hs[row * 20 + q * 4] = v;
  }
  __syncthreads();

  // ---- im2col gather from Hs into registers ----
  const int m = t >> 3, sub = t & 7;
  const int ox = m & 7;
  const int my = (m >> 3) * 2;                // 2*(m>>3)
  ushort_t tv[54];
  int j = 0;
#pragma unroll
  for (int ic2 = 0; ic2 < 2; ++ic2) {
    const int ic = sub * 2 + ic2;
#pragma unroll
    for (int dz = 0; dz < 3; ++dz) {
#pragma unroll
      for (int dy = 0; dy < 3; ++dy) {
        const int row = ic * 18 + dz * 6 + my + dy;
        const unsigned* rp = Hsd + row * 10;
        const unsigned d0 = (ox > 0) ? rp[ox - 1] : 0u;
        const unsigned d1 = rp[ox];
        tv[j]     = (ushort_t)(d0 >> 16);     // ix = 2ox-1
        tv[j + 1] = (ushort_t)(d1 & 0xFFFFu); // ix = 2ox
        tv[j + 2] = (ushort_t)(d1 >> 16);     // ix = 2ox+1
        j += 3;
      }
    }
  }
  __syncthreads();                            // Hs fully consumed

  // ---- write As (overwrites Hs region) + K-pad zeros ----
  {
    unsigned* Aw = (unsigned*)As;
    const int wbase = m * 228 + sub * 27;
#pragma unroll
    for (int p = 0; p < 27; ++p)
      Aw[wbase + p] = (unsigned)tv[2 * p] | ((unsigned)tv[2 * p + 1] << 16);
    Aw[(t >> 3) * 228 + 216 + (t & 7)] = 0u;  // k in [432,448)
  }
  __syncthreads();

  // ---- MFMA + store (bf16) ----
  f32x4 acc = {0.f, 0.f, 0.f, 0.f};
  const ushort_t* arow = &As[(l & 15) * 456 + ((l >> 4) << 3)];
#pragma unroll
  for (int kk = 0; kk < 14; ++kk) {
    const bf16x8 af = *(const bf16x8*)(const void*)&arow[kk * 32];
    acc = __builtin_amdgcn_mfma_f32_16x16x32_bf16(af, bfr[kk], acc, 0, 0, 0);
  }
  const int n = w * 16 + (l & 15);
  const int m0 = (l >> 4) << 2;
  ushort_t* cb = c2b + (((size_t)(bn * 32 + n) * 8) + oz) * 64 + yg * 16 + m0;
  const unsigned lo = (unsigned)f2bf(acc[0]) | ((unsigned)f2bf(acc[1]) << 16);
  const unsigned hi = (unsigned)f2bf(acc[2]) | ((unsigned)f2bf(acc[3]) << 16);
  *(uint2*)cb = make_uint2(lo, hi);
}

// ---------------- GCN layer body (X@W then A@P), used by k_tail ------------
// (R8 depth-2 prefetch form — measured neutral vs depth-1, kept.)
__device__ __forceinline__ void gcn_body(
    const ushort_t* __restrict__ Xb, const ushort_t* __restrict__ WT,
    const float* __restrict__ bias, const float* __restrict__ An,
    ushort_t* __restrict__ Ob, float* __restrict__ spw,
    int K, int N, int relu, int b, int jb,
    ushort_t (*As)[64 * 72], ushort_t (*Bs)[64 * 72], ushort_t* Ps)
{
  const int t = threadIdx.x, w = t >> 6, l = t & 63;
  const int r0 = t >> 3, kc0 = t & 7;
  const int lm = l & 15, lg = l >> 4;

  union { short s[8]; bf16x8 v; } afr[2];
  {
    const float* ap = An + b * 4096 + (16 * w + lm) * 64 + (lg << 3);
#pragma unroll
    for (int kc = 0; kc < 2; ++kc) {
      const float4 v0 = *(const float4*)(ap + kc * 32);
      const float4 v1 = *(const float4*)(ap + kc * 32 + 4);
      afr[kc].s[0] = (short)f2bf(v0.x); afr[kc].s[1] = (short)f2bf(v0.y);
      afr[kc].s[2] = (short)f2bf(v0.z); afr[kc].s[3] = (short)f2bf(v0.w);
      afr[kc].s[4] = (short)f2bf(v1.x); afr[kc].s[5] = (short)f2bf(v1.y);
      afr[kc].s[6] = (short)f2bf(v1.z); afr[kc].s[7] = (short)f2bf(v1.w);
    }
  }

  f32x4 acc[4];
#pragma unroll
  for (int nt = 0; nt < 4; ++nt) acc[nt] = (f32x4){0.f, 0.f, 0.f, 0.f};

  const ushort_t* arow0 = &Xb[(size_t)(b * 64 + r0) * K + kc0 * 8];
  const ushort_t* arow1 = &Xb[(size_t)(b * 64 + r0 + 32) * K + kc0 * 8];
  const ushort_t* brow0 = &WT[(size_t)(jb + r0) * K + kc0 * 8];
  const ushort_t* brow1 = &WT[(size_t)(jb + r0 + 32) * K + kc0 * 8];

  // prologue: set A holds kt=0, set B holds kt=64 (K >= 128 always)
  uint4 vaA0 = *(const uint4*)arow0;
  uint4 vaA1 = *(const uint4*)arow1;
  uint4 vbA0 = *(const uint4*)brow0;
  uint4 vbA1 = *(const uint4*)brow1;
  uint4 vaB0 = *(const uint4*)(arow0 + 64);
  uint4 vaB1 = *(const uint4*)(arow1 + 64);
  uint4 vbB0 = *(const uint4*)(brow0 + 64);
  uint4 vbB1 = *(const uint4*)(brow1 + 64);

  int buf = 0;
#pragma unroll 1
  for (int kt = 0; kt < K; kt += 128) {
    // ---- sub-iter A: data kt; prefetch kt+128 into set A ----
    *(uint4*)&As[buf][r0 * 72 + kc0 * 8]        = vaA0;
    *(uint4*)&As[buf][(r0 + 32) * 72 + kc0 * 8] = vaA1;
    *(uint4*)&Bs[buf][r0 * 72 + kc0 * 8]        = vbA0;
    *(uint4*)&Bs[buf][(r0 + 32) * 72 + kc0 * 8] = vbA1;
    __syncthreads();
    if (kt + 128 < K) {
      vaA0 = *(const uint4*)(arow0 + kt + 128);
      vaA1 = *(const uint4*)(arow1 + kt + 128);
      vbA0 = *(const uint4*)(brow0 + kt + 128);
      vbA1 = *(const uint4*)(brow1 + kt + 128);
    }
#pragma unroll
    for (int ks = 0; ks < 2; ++ks) {
      const bf16x8 af = *(const bf16x8*)(const void*)
          &As[buf][(16 * w + lm) * 72 + ks * 32 + (lg << 3)];
#pragma unroll
      for (int nt = 0; nt < 4; ++nt) {
        const bf16x8 bf = *(const bf16x8*)(const void*)
            &Bs[buf][(nt * 16 + lm) * 72 + ks * 32 + (lg << 3)];
        acc[nt] = __builtin_amdgcn_mfma_f32_16x16x32_bf16(af, bf, acc[nt], 0, 0, 0);
      }
    }
    buf ^= 1;
    // ---- sub-iter B: data kt+64; prefetch kt+192 into set B ----
    *(uint4*)&As[buf][r0 * 72 + kc0 * 8]        = vaB0;
    *(uint4*)&As[buf][(r0 + 32) * 72 + kc0 * 8] = vaB1;
    *(uint4*)&Bs[buf][r0 * 72 + kc0 * 8]        = vbB0;
    *(uint4*)&Bs[buf][(r0 + 32) * 72 + kc0 * 8] = vbB1;
    __syncthreads();
    if (kt + 192 < K) {
      vaB0 = *(const uint4*)(arow0 + kt + 192);
      vaB1 = *(const uint4*)(arow1 + kt + 192);
      vbB0 = *(const uint4*)(brow0 + kt + 192);
      vbB1 = *(const uint4*)(brow1 + kt + 192);
    }
#pragma unroll
    for (int ks = 0; ks < 2; ++ks) {
      const bf16x8 af = *(const bf16x8*)(const void*)
          &As[buf][(16 * w + lm) * 72 + ks * 32 + (lg << 3)];
#pragma unroll
      for (int nt = 0; nt < 4; ++nt) {
        const bf16x8 bf = *(const bf16x8*)(const void*)
            &Bs[buf][(nt * 16 + lm) * 72 + ks * 32 + (lg << 3)];
        acc[nt] = __builtin_amdgcn_mfma_f32_16x16x32_bf16(af, bf, acc[nt], 0, 0, 0);
      }
    }
    buf ^= 1;
  }

  __syncthreads();
  const int m0 = lg << 2;
#pragma unroll
  for (int nt = 0; nt < 4; ++nt) {
    const int n = nt * 16 + lm;
    const unsigned lo = (unsigned)f2bf(acc[nt][0]) | ((unsigned)f2bf(acc[nt][1]) << 16);
    const unsigned hi = (unsigned)f2bf(acc[nt][2]) | ((unsigned)f2bf(acc[nt][3]) << 16);
    *(uint2*)&Ps[n * 72 + 16 * w + m0] = make_uint2(lo, hi);
  }
  __syncthreads();

  float mx0 = -1e30f, mx1 = -1e30f, mx2 = -1e30f, mx3 = -1e30f;
#pragma unroll
  for (int nt = 0; nt < 4; ++nt) {
    const bf16x8 b0 = *(const bf16x8*)(const void*)&Ps[(nt * 16 + lm) * 72 + (lg << 3)];
    const bf16x8 b1 = *(const bf16x8*)(const void*)&Ps[(nt * 16 + lm) * 72 + 32 + (lg << 3)];
    f32x4 a2 = (f32x4){0.f, 0.f, 0.f, 0.f};
    a2 = __builtin_amdgcn_mfma_f32_16x16x32_bf16(afr[0].v, b0, a2, 0, 0, 0);
    a2 = __builtin_amdgcn_mfma_f32_16x16x32_bf16(afr[1].v, b1, a2, 0, 0, 0);
    const int col = jb + nt * 16 + lm;
    const float bv = bias[col];
    if (spw) {
      mx0 = fmaxf(mx0, a2[0] + bv);
      mx1 = fmaxf(mx1, a2[1] + bv);
      mx2 = fmaxf(mx2, a2[2] + bv);
      mx3 = fmaxf(mx3, a2[3] + bv);
    } else {
#pragma unroll
      for (int r = 0; r < 4; ++r) {
        const int row = b * 64 + 16 * w + m0 + r;
        float v = a2[r] + bv;
        if (relu) v = fmaxf(v, 0.f);
        Ob[(size_t)row * N + col] = f2bf(v);
      }
    }
  }
  if (spw) {
    // reduce over the 16 lm lanes (bits 0..3 of lane id); w/lg preserved
#pragma unroll
    for (int mk = 1; mk <= 8; mk <<= 1) {
      mx0 = fmaxf(mx0, __shfl_xor(mx0, mk));
      mx1 = fmaxf(mx1, __shfl_xor(mx1, mk));
      mx2 = fmaxf(mx2, __shfl_xor(mx2, mk));
      mx3 = fmaxf(mx3, __shfl_xor(mx3, mk));
    }
    if (lm == 0) {
      const int c = jb >> 6;
      const int n = 16 * w + m0;
      spw[b * 256 + (n + 0) * 4 + c] = mx0;
      spw[b * 256 + (n + 1) * 4 + c] = mx1;
      spw[b * 256 + (n + 2) * 4 + c] = mx2;
      spw[b * 256 + (n + 3) * 4 + c] = mx3;
    }
  }
}

// ---------------- fused tail: pool2 | gcn x3 | fc1 | fc2 -------------------
// Plain launch, 512 blocks x 256 threads. Phase 0 = maxpool(conv2)+bias+relu
// (all 512 blocks, bf16 c2 reads); blocks >=64 arrive at barrier 0 and exit.
// Blocks 0..63 run the proven gcn/fc pipeline with 64-arrival barriers.
// Wait sets: b0: blocks<64 (featb); b1: <32 (g1b); b2: <16 (g2b);
// b3: all 64 (spw); b4: <4 (shw).
__global__ __launch_bounds__(256) void k_tail(
    const ushort_t* __restrict__ c2b, const float* __restrict__ bc2,
    ushort_t* __restrict__ featb,
    const ushort_t* __restrict__ wg1T, const float* __restrict__ bg1,
    const ushort_t* __restrict__ wg2T, const float* __restrict__ bg2,
    const ushort_t* __restrict__ wg3T, const float* __restrict__ bg3,
    const float* __restrict__ An,
    ushort_t* __restrict__ g1b, ushort_t* __restrict__ g2b,
    float* __restrict__ spw, float* __restrict__ shw,
    const float* __restrict__ w1, const float* __restrict__ b1,
    const float* __restrict__ w2, const float* __restrict__ b2,
    float* __restrict__ out, int* __restrict__ bar)
{
  __shared__ ushort_t As[2][64 * 72];
  __shared__ ushort_t Bs[2][64 * 72];
  __shared__ ushort_t Ps[64 * 72];
  __shared__ float red[260];
  const int bx = blockIdx.x, t = threadIdx.x;

  // phase 0: maxpool3 s2 p1 + bias + relu -> featb (bf16 in, bf16 out)
  {
    const int tid = bx * 256 + t;              // 131072
    const int bn = tid >> 9, r = tid & 511;
    const int ch = r >> 4, pz = (r >> 2) & 3, py = r & 3;
    const ushort_t* base = c2b + ((size_t)(bn * 32 + ch) << 9);
    float m0 = -1e30f, m1 = -1e30f, m2 = -1e30f, m3 = -1e30f;
#pragma unroll
    for (int dz = 0; dz < 3; ++dz) {
      const int oz = 2 * pz - 1 + dz;
      if ((unsigned)oz >= 8u) continue;
#pragma unroll
      for (int dy = 0; dy < 3; ++dy) {
        const int oy = 2 * py - 1 + dy;
        if ((unsigned)oy >= 8u) continue;
        const uint4 v = *(const uint4*)(base + (oz << 6) + (oy << 3));
        const float x0 = __uint_as_float((v.x & 0xFFFFu) << 16);
        const float x1 = __uint_as_float(v.x & 0xFFFF0000u);
        const float x2 = __uint_as_float((v.y & 0xFFFFu) << 16);
        const float x3 = __uint_as_float(v.y & 0xFFFF0000u);
        const float x4 = __uint_as_float((v.z & 0xFFFFu) << 16);
        const float x5 = __uint_as_float(v.z & 0xFFFF0000u);
        const float x6 = __uint_as_float((v.w & 0xFFFFu) << 16);
        const float x7 = __uint_as_float(v.w & 0xFFFF0000u);
        m0 = fmaxf(m0, fmaxf(x0, x1));
        m1 = fmaxf(m1, fmaxf(x1, fmaxf(x2, x3)));
        m2 = fmaxf(m2, fmaxf(x3, fmaxf(x4, x5)));
        m3 = fmaxf(m3, fmaxf(x5, fmaxf(x6, x7)));
      }
    }
    const float bb = bc2[ch];
    const unsigned lo = (unsigned)f2bf(fmaxf(m0 + bb, 0.f)) |
                        ((unsigned)f2bf(fmaxf(m1 + bb, 0.f)) << 16);
    const unsigned hi = (unsigned)f2bf(fmaxf(m2 + bb, 0.f)) |
                        ((unsigned)f2bf(fmaxf(m3 + bb, 0.f)) << 16);
    *(uint2*)(featb + (size_t)bn * 2048 + r * 4) = make_uint2(lo, hi);
  }
  gbar(bar, 0, 512, bx < 64);
  if (bx >= 64) return;

  // phase 1: gcn1  (all 64 blocks: 16 col-tiles x 4 graphs)
  gcn_body(featb, wg1T, bg1, An, g1b, nullptr, 2048, 1024, 1,
           bx >> 4, (bx & 15) << 6, As, Bs, Ps);
  gbar(bar, 1, 64, bx < 32);

  // phase 2: gcn2  (32 blocks: 8 col-tiles x 4 graphs)
  if (bx < 32)
    gcn_body(g1b, wg2T, bg2, An, g2b, nullptr, 1024, 512, 1,
             bx >> 3, (bx & 7) << 6, As, Bs, Ps);
  gbar(bar, 2, 64, bx < 16);

  // phase 3: gcn3 + fused 64-chunk max (16 blocks: 4 col-tiles x 4 graphs)
  if (bx < 16)
    gcn_body(g2b, wg3T, bg3, An, nullptr, spw, 512, 256, 0,
             bx >> 2, (bx & 3) << 6, As, Bs, Ps);
  gbar(bar, 3, 64, true);

  // phase 4: fc1 distributed: 2048 outputs over 64 blocks (32 each),
  // 8-way K-split per output + LDS reduce.
  {
    const int oo = t & 31, ks = t >> 5;          // ks in 0..7
    const int bb = bx >> 4;                      // graph
    const int jj = (bx & 15) * 32 + oo;          // fc1 column
    const float* spb = spw + bb * 256;
    float s = 0.f;
#pragma unroll
    for (int i = 0; i < 32; ++i) {
      const int k = ks * 32 + i;
      s += spb[k] * w1[k * 512 + jj];
    }
    red[t] = s;
    __syncthreads();
    if (t < 32) {
      float s2 = 0.f;
#pragma unroll
      for (int i = 0; i < 8; ++i) s2 += red[t + i * 32];
      const int j2 = (bx & 15) * 32 + t;
      shw[bb * 512 + j2] = fmaxf(s2 + b1[j2], 0.f);
    }
  }
  gbar(bar, 4, 64, bx < 4);

  // phase 5: fc2 + softmax (blocks 0..3, one per graph)
  if (bx < 4) {
    float s = 0.f;
    if (t < 128) {
      const int c = t & 3, ks2 = t >> 2;         // ks2 in 0..31
      const float* shb = shw + bx * 512;
#pragma unroll
      for (int i = 0; i < 16; ++i) {
        const int k = ks2 * 16 + i;
        s += shb[k] * w2[k * 4 + c];
      }
    }
    red[t] = s;
    __syncthreads();
    if (t < 4) {
      float s2 = b2[t];
#pragma unroll
      for (int i = 0; i < 32; ++i) s2 += red[t + i * 4];
      red[256 + t] = s2;
    }
    __syncthreads();
    if (t == 0) {
      const float a0 = red[256], a1 = red[257], a2v = red[258], a3 = red[259];
      const float mm = fmaxf(fmaxf(a0, a1), fmaxf(a2v, a3));
      const float e0 = expf(a0 - mm), e1 = expf(a1 - mm);
      const float e2 = expf(a2v - mm), e3 = expf(a3 - mm);
      const float inv = 1.f / (e0 + e1 + e2 + e3);
      out[bx * 4 + 0] = e0 * inv;
      out[bx * 4 + 1] = e1 * inv;
      out[bx * 4 + 2] = e2 * inv;
      out[bx * 4 + 3] = e3 * inv;
    }
  }
}

// ---------------------------------------------------------------------------
extern "C" void kernel_launch(void* const* d_in, const int* in_sizes, int n_in,
                              void* d_out, int out_size, void* d_ws, size_t ws_size,
                              hipStream_t stream)
{
  (void)in_sizes; (void)n_in; (void)out_size; (void)ws_size;
  const float* x   = (const float*)d_in[0];
  const int*   adj = (const int*)d_in[1];
  const float* wc1 = (const float*)d_in[3];
  const float* bc1 = (const float*)d_in[4];
  const float* wc2 = (const float*)d_in[5];
  const float* bc2 = (const float*)d_in[6];
  const float* wg1 = (const float*)d_in[7];
  const float* bg1 = (const float*)d_in[8];
  const float* wg2 = (const float*)d_in[9];
  const float* bg2 = (const float*)d_in[10];
  const float* wg3 = (const float*)d_in[11];
  const float* bg3 = (const float*)d_in[12];
  const float* wf1 = (const float*)d_in[13];
  const float* bf1 = (const float*)d_in[14];
  const float* wf2 = (const float*)d_in[15];
  const float* bf2 = (const float*)d_in[16];

  float* ws    = (float*)d_ws;
  ushort_t* h1 = (ushort_t*)d_ws;
  ushort_t* w2f   = (ushort_t*)(ws + 8388608);
  ushort_t* wg1Tb = (ushort_t*)(ws + 8395776);
  ushort_t* wg2Tb = (ushort_t*)(ws + 9444352);
  ushort_t* wg3Tb = (ushort_t*)(ws + 9706496);
  ushort_t* featb = (ushort_t*)(ws + 9772032);
  ushort_t* g1b   = (ushort_t*)(ws + 10034176);
  ushort_t* g2b   = (ushort_t*)(ws + 10165248);
  ushort_t* c2b  = (ushort_t*)(ws + 16777216);   // bf16; aliases xb16 region
  ushort_t* xb16 = (ushort_t*)(ws + 16777216);   // consumed pre-conv2
  float* An   = ws + 21495808;
  float* spw  = ws + 2621440;                    // in h1 region (dead after conv2)
  float* shw  = ws + 2622464;                    // in h1 region
  int*   bar  = (int*)(ws + 22364160);           // 5 x 1024-int barrier states
  float* outp = (float*)d_out;

  hipLaunchKernelGGL(k_prep,        dim3(10940),    dim3(256), 0, stream,
                     x, xb16, wc2, w2f, wg1, wg1Tb, wg2, wg2Tb, wg3, wg3Tb, adj, An);
  hipLaunchKernelGGL(k_conv1_mfma,  dim3(2048),     dim3(256), 0, stream, xb16, wc1, bc1, h1);
  hipLaunchKernelGGL(k_conv2,       dim3(8192),     dim3(128), 0, stream, h1, w2f, c2b, bar);
  hipLaunchKernelGGL(k_tail,        dim3(512),      dim3(256), 0, stream,
                     c2b, bc2, featb, wg1Tb, bg1, wg2Tb, bg2, wg3Tb, bg3, An,
                     g1b, g2b, spw, shw, wf1, bf1, wf2, bf2, outp, bar);
}

// Round 10
// 251.015 us; speedup vs baseline: 1.0866x; 1.0866x over previous
//
#include <hip/hip_runtime.h>

typedef unsigned short ushort_t;
typedef unsigned long long ull_t;
typedef __attribute__((ext_vector_type(8))) short bf16x8;
typedef __attribute__((ext_vector_type(4))) float f32x4;

static __device__ __forceinline__ unsigned short f2bf(float f) {
  unsigned u = __float_as_uint(f);
  u = (u + 0x7FFFu + ((u >> 16) & 1u)) >> 16;
  return (unsigned short)u;
}

static __device__ __forceinline__ f32x4 max4(f32x4 a, f32x4 b) {
  f32x4 r;
  r[0] = fmaxf(a[0], b[0]); r[1] = fmaxf(a[1], b[1]);
  r[2] = fmaxf(a[2], b[2]); r[3] = fmaxf(a[3], b[3]);
  return r;
}

// Single-use hierarchical grid barrier, one state block per barrier id.
// R7/R8 measured: barrier design moves the tail <2us. R9 measured: >64
// arrivals regresses (64 serialized RMWs/leaf) — keep nb=64 only.
// Layout per barrier: leaf[i]@i*32 (i<8), root@256, gen[i]@288+i*32.
static __device__ __forceinline__ void gbar(int* bar0, int bid, int nb,
                                            bool do_wait) {
  __syncthreads();
  if (threadIdx.x == 0) {
    int* bar = bar0 + (bid << 10);
    __threadfence();                        // release
    const int leaf = (blockIdx.x & 7) << 5;
    const int nleaf = nb >> 3;
    if (__hip_atomic_fetch_add(&bar[leaf], 1, __ATOMIC_ACQ_REL,
                               __HIP_MEMORY_SCOPE_AGENT) == nleaf - 1) {
      if (__hip_atomic_fetch_add(&bar[256], 1, __ATOMIC_ACQ_REL,
                                 __HIP_MEMORY_SCOPE_AGENT) == 7) {
#pragma unroll
        for (int i = 0; i < 8; ++i)
          __hip_atomic_store(&bar[288 + (i << 5)], 1, __ATOMIC_RELEASE,
                             __HIP_MEMORY_SCOPE_AGENT);
      }
    }
    if (do_wait) {
      int* mygen = &bar[288 + leaf];
      for (int it = 0; it < (1 << 22); ++it) {
        if (__hip_atomic_load(mygen, __ATOMIC_RELAXED,
                              __HIP_MEMORY_SCOPE_AGENT) != 0) break;
        __builtin_amdgcn_s_sleep(2);
      }
      __threadfence();                      // acquire
    }
  }
  __syncthreads();
}

// ---------------------------------------------------------------------------
// Workspace layout (fp32-element offsets):
//   h1    @ 0          : 16777216 ushorts (dead after conv2; spw/shw reuse it)
//     spw @ 2621440    : 1024 floats (chunk-max output)
//     shw @ 2622464    : 2048 floats (fc1 output)
//   w2f   @ 8388608    : 14336 ushorts (conv2 weight frags)
//   wg1Tb @ 8395776    : 1024x2048 ushorts
//   wg2Tb @ 9444352    : 512x1024 ushorts
//   wg3Tb @ 9706496    : 256x512 ushorts
//   featb @ 9772032    : 256x2048 ushorts
//   g1b   @ 10034176   : 256x1024 ushorts
//   g2b   @ 10165248   : 256x512 ushorts
//   c2b   @ 16777216   : 4194304 ushorts bf16 (ALIASED: xb16, consumed pre-conv2)
//   An    @ 21495808   : 4*64*64
//   bar   @ 22364160   : 4096 ints (4 single-use barrier states x 1024)
// ---------------------------------------------------------------------------

// ---------------- fused prep: x2bf | w2f | 3x transpose | gcn_norm ---------
__device__ __forceinline__ void prep_transpose(
    const float* __restrict__ W, ushort_t* __restrict__ out,
    int K, int N, int n0, int k0, int t, float (*tile)[33])
{
  const int tx = t & 31, ty = t >> 5;
#pragma unroll
  for (int i = 0; i < 4; ++i) {
    const int k = k0 + ty + i * 8;
    tile[ty + i * 8][tx] = W[(size_t)k * N + n0 + tx];
  }
  __syncthreads();
#pragma unroll
  for (int i = 0; i < 4; ++i) {
    const int n = n0 + ty + i * 8;
    out[(size_t)n * K + k0 + tx] = f2bf(tile[tx][ty + i * 8]);
  }
}

__global__ __launch_bounds__(256) void k_prep(
    const float* __restrict__ x, ushort_t* __restrict__ xb16,
    const float* __restrict__ w2, ushort_t* __restrict__ w2f,
    const float* __restrict__ wg1, ushort_t* __restrict__ wg1T,
    const float* __restrict__ wg2, ushort_t* __restrict__ wg2T,
    const float* __restrict__ wg3, ushort_t* __restrict__ wg3T,
    const int* __restrict__ adj, float* __restrict__ An)
{
  __shared__ float tile[32][33];
  __shared__ float dinv[64];
  __shared__ int part[256];
  int b = blockIdx.x;
  const int t = threadIdx.x;
  if (b < 8192) {                       // x -> bf16
    const int tid = b * 256 + t;
    const float4 v = ((const float4*)x)[tid];
    const unsigned lo = (unsigned)f2bf(v.x) | ((unsigned)f2bf(v.y) << 16);
    const unsigned hi = (unsigned)f2bf(v.z) | ((unsigned)f2bf(v.w) << 16);
    ((uint2*)xb16)[tid] = make_uint2(lo, hi);
    return;
  }
  b -= 8192;
  if (b < 56) {                         // conv2 weight frags
    const int tid = b * 256 + t;
    if (tid < 14336) {
      const int nt = tid / 7168, rem = tid % 7168;
      const int kk = rem / 512, rem2 = rem % 512;
      const int l = rem2 >> 3, j = rem2 & 7;
      const int n = nt * 16 + (l & 15);
      const int k = (l >> 4) * 8 + kk * 32 + j;
      float v = 0.f;
      if (k < 432) v = w2[n * 432 + k];
      w2f[tid] = f2bf(v);
    }
    return;
  }
  b -= 56;
  if (b < 2048) { prep_transpose(wg1, wg1T, 2048, 1024, (b & 31) << 5, (b >> 5) << 5, t, tile); return; }
  b -= 2048;
  if (b < 512)  { prep_transpose(wg2, wg2T, 1024, 512,  (b & 15) << 5, (b >> 4) << 5, t, tile); return; }
  b -= 512;
  if (b < 128)  { prep_transpose(wg3, wg3T, 512,  256,  (b & 7)  << 5, (b >> 3) << 5, t, tile); return; }
  b -= 128;
  {                                     // gcn_norm, b in [0,4)
    const int i = t >> 2, q = t & 3;
    const int* ab = adj + b * 4096 + i * 64 + q * 16;
    int d = 0;
#pragma unroll
    for (int j = 0; j < 16; ++j) d += (ab[j] != 0) ? 1 : 0;
    part[t] = d;
    __syncthreads();
    if (q == 0)
      dinv[i] = rsqrtf((float)(1 + part[t] + part[t + 1] + part[t + 2] + part[t + 3]));
    __syncthreads();
    for (int idx = t; idx < 4096; idx += 256) {
      const int ii = idx >> 6, jj = idx & 63;
      const float a = (ii == jj) ? 1.f : ((adj[b * 4096 + idx] != 0) ? 1.f : 0.f);
      An[b * 4096 + idx] = a * dinv[ii] * dinv[jj];
    }
  }
}

// ---------------- K1: conv1 + maxpool3 as bf16 MFMA "pooled-direct" --------
// (R8 form — measured best; do not touch.)
__global__ __launch_bounds__(256) void k_conv1_mfma(
    const ushort_t* __restrict__ xb16, const float* __restrict__ wc,
    const float* __restrict__ bc, ushort_t* __restrict__ h1)
{
  __shared__ ushort_t L[2 * 34 * 76];
  char* Lb = (char*)L;
  const int bn = blockIdx.x >> 3, zg = blockIdx.x & 7;
  const int t = threadIdx.x;
  const int w = t >> 6, l = t & 63;
  const int grp = l >> 4, m = l & 15, ch = l & 15;
  const float NINF = -1e30f;

  union { short s[8]; bf16x8 v; } uA, uB;
#pragma unroll
  for (int j = 0; j < 8; ++j) {
    const int k = grp * 8 + j;
    float wA = 0.f, wB = 0.f;
    if (k < 12) {
      const int dx = k >> 2, dz = k & 3;
      if (dz < 3) { wA = wc[ch*27 + dz*9 + 0 + dx]; wB = wc[ch*27 + dz*9 + 6 + dx]; }
    } else if (k >= 16 && k < 28) {
      const int kk = k - 16, dx = kk >> 2, dz = kk & 3;
      if (dz < 3) wA = wc[ch*27 + dz*9 + 3 + dx];
    }
    uA.s[j] = (short)f2bf(wA);
    uB.s[j] = (short)f2bf(wB);
  }

  int aX1[3], aX2[3];
#pragma unroll
  for (int s = 0; s < 3; ++s) {
    const int Q1 = 2*m + s + 2*(grp & 1);
    const int Q2 = Q1 + 1;
    aX1[s] = (Q1 & 1) * 5168 + (Q1 >> 1) * 8;
    aX2[s] = (Q2 & 1) * 5168 + (Q2 >> 1) * 8;
  }
  const int rsel = (grp >> 1) * 152;

  for (int u = t; u < 200; u += 256) {
    int addr;
    if (u < 72) {
      const int rr = (u < 36) ? 0 : 33;
      const int s = (u < 36) ? u : u - 36;
      const int pp = s / 18, slot = s - pp * 18;
      addr = pp * 5168 + rr * 152 + slot * 8;
    } else {
      const int v = u - 72;
      const int rr = 1 + (v >> 2);
      const int pp = (v >> 1) & 1;
      const int slot = (v & 1) * 17;
      addr = pp * 5168 + rr * 152 + slot * 8;
    }
    *(ull_t*)(Lb + addr) = 0ull;
  }

  f32x4 accZ[4][2];
#pragma unroll
  for (int j = 0; j < 4; ++j)
#pragma unroll
    for (int p = 0; p < 2; ++p) accZ[j][p] = (f32x4){NINF, NINF, NINF, NINF};

  const ushort_t* xb = xb16 + (size_t)bn * 32768;

#pragma unroll 1
  for (int ci = 0; ci < 5; ++ci) {
    const int cz = 4*zg - 1 + ci;
    if (cz < 0) continue;
    if (t < 128) {
      const int r = 1 + (t >> 2), g = t & 3;
      const ushort_t* xrow = xb + (r - 1) * 32 + g * 8;
      uint4 u0 = make_uint4(0u, 0u, 0u, 0u), u2 = make_uint4(0u, 0u, 0u, 0u);
      if (cz > 0)  u0 = *(const uint4*)(xrow + (cz - 1) * 1024);
      const uint4 u1 = *(const uint4*)(xrow + cz * 1024);
      if (cz < 31) u2 = *(const uint4*)(xrow + (cz + 1) * 1024);
      char* b0 = Lb + r * 152 + (4 * g + 1) * 8;
      char* b1 = Lb + 5168 + r * 152 + (4 * g + 1) * 8;
      const unsigned* p0 = (const unsigned*)&u0;
      const unsigned* p1 = (const unsigned*)&u1;
      const unsigned* p2 = (const unsigned*)&u2;
#pragma unroll
      for (int e = 0; e < 4; ++e) {
        const unsigned w0 = p0[e], w1 = p1[e], w2v = p2[e];
        const unsigned lo_e = (w0 & 0xFFFFu) | (w1 << 16);
        const unsigned hi_e = (w2v & 0xFFFFu);
        const unsigned lo_o = (w0 >> 16) | (w1 & 0xFFFF0000u);
        const unsigned hi_o = (w2v >> 16);
        *(ull_t*)(b0 + e * 8) = (ull_t)lo_e | ((ull_t)hi_e << 32);
        *(ull_t*)(b1 + e * 8) = (ull_t)lo_o | ((ull_t)hi_o << 32);
      }
    }
    __syncthreads();
    f32x4 accP0 = (f32x4){NINF, NINF, NINF, NINF};
    f32x4 accP1 = (f32x4){NINF, NINF, NINF, NINF};
#pragma unroll
    for (int yy = 0; yy < 9; ++yy) {
      if (yy == 0 && w == 0) continue;
      const int y = 8 * w - 1 + yy;
      const int rbA = y * 152 + rsel;
      const int rbB = (y + 2) * 152;
      f32x4 Cy;
#pragma unroll
      for (int s = 0; s < 3; ++s) {
        union { ull_t u[2]; bf16x8 v; } fA, fB;
        fA.u[0] = *(const ull_t*)(Lb + aX1[s] + rbA);
        fA.u[1] = *(const ull_t*)(Lb + aX2[s] + rbA);
        fB.u[0] = *(const ull_t*)(Lb + aX1[s] + rbB);
        fB.u[1] = *(const ull_t*)(Lb + aX2[s] + rbB);
        f32x4 acc = (f32x4){0.f, 0.f, 0.f, 0.f};
        acc = __builtin_amdgcn_mfma_f32_16x16x32_bf16(fA.v, uA.v, acc, 0, 0, 0);
        acc = __builtin_amdgcn_mfma_f32_16x16x32_bf16(fB.v, uB.v, acc, 0, 0, 0);
        if (s == 0) acc[0] = (l < 16) ? NINF : acc[0];
        Cy = (s == 0) ? acc : max4(Cy, acc);
      }
      if (yy & 1) {
        const int c = (yy - 1) / 2;
        if ((c & 1) == 0) accP0 = max4(accP0, Cy); else accP1 = max4(accP1, Cy);
      } else {
        const int cl = yy / 2 - 1;
        const int chh = yy / 2;
        if (cl >= 0) {
          if ((cl & 1) == 0) {
            accP0 = max4(accP0, Cy);
            if (ci <= 2) accZ[cl][0] = max4(accZ[cl][0], accP0);
            if (ci >= 2) accZ[cl][1] = max4(accZ[cl][1], accP0);
            accP0 = (f32x4){NINF, NINF, NINF, NINF};
          } else {
            accP1 = max4(accP1, Cy);
            if (ci <= 2) accZ[cl][0] = max4(accZ[cl][0], accP1);
            if (ci >= 2) accZ[cl][1] = max4(accZ[cl][1], accP1);
            accP1 = (f32x4){NINF, NINF, NINF, NINF};
          }
        }
        if (chh <= 3) {
          if ((chh & 1) == 0) accP0 = max4(accP0, Cy); else accP1 = max4(accP1, Cy);
        }
      }
    }
    __syncthreads();
  }

  const float biasv = bc[ch];
#pragma unroll
  for (int j = 0; j < 4; ++j) {
    const int py = 4 * w + j;
#pragma unroll
    for (int p = 0; p < 2; ++p) {
      const int pz = 2 * zg + p;
      const f32x4 v = accZ[j][p];
      const unsigned lo = (unsigned)f2bf(fmaxf(v[0] + biasv, 0.f)) |
                          ((unsigned)f2bf(fmaxf(v[1] + biasv, 0.f)) << 16);
      const unsigned hi = (unsigned)f2bf(fmaxf(v[2] + biasv, 0.f)) |
                          ((unsigned)f2bf(fmaxf(v[3] + biasv, 0.f)) << 16);
      ushort_t* dst = h1 + (((size_t)(bn * 16 + ch) * 16 + pz) << 8) + py * 16 + grp * 4;
      *(uint2*)dst = make_uint2(lo, hi);
    }
  }
}

// ---------------- K2: conv2 MFMA implicit GEMM, LDS-staged input -----------
// bf16 output (R9's orthogonal win, kept: halves conv2-write + pool-read).
__global__ __launch_bounds__(128) void k_conv2(
    const ushort_t* __restrict__ h1, const ushort_t* __restrict__ w2f,
    ushort_t* __restrict__ c2b)
{
  __shared__ ushort_t U[16 * 456];            // 14592 B: Hs (11520 B) then As
  ushort_t* Hs = U;                           // Hs[row*20 + ix], row<288
  unsigned* Hsd = (unsigned*)U;               // dword view, stride 10
  ushort_t* As = U;                           // As[m*456 + k]
  const int b = blockIdx.x;
  const int bn = b >> 5, oz = (b >> 2) & 7, yg = b & 3;
  const int t = threadIdx.x;
  const ushort_t* hb = h1 + ((size_t)bn << 16);
  const int w = t >> 6, l = t & 63;

  bf16x8 bfr[14];
#pragma unroll
  for (int kk = 0; kk < 14; ++kk)
    bfr[kk] = *(const bf16x8*)(const void*)&w2f[(((w * 14) + kk) * 64 + l) * 8];

  // ---- stage Hs: 288 rows x 4 uint2-quads, coalesced, OOB -> 0 ----
#pragma unroll
  for (int it = 0; it < 9; ++it) {
    const int u = t + it * 128;               // 0..1151
    const int row = u >> 2, q = u & 3;
    const int ic = row / 18;
    const int r2 = row - ic * 18;
    const int izp = r2 / 6;
    const int iyp = r2 - izp * 6;
    const int iz = 2 * oz - 1 + izp;
    const int iy = 4 * yg - 1 + iyp;
    uint2 v = make_uint2(0u, 0u);
    if ((unsigned)iz < 16u && (unsigned)iy < 16u)
      v = *(const uint2*)(hb + (ic << 12) + (iz << 8) + (iy << 4) + q * 4);
    *(uint2*)&Hs[row * 20 + q * 4] = v;
  }
  __syncthreads();

  // ---- im2col gather from Hs into registers ----
  const int m = t >> 3, sub = t & 7;
  const int ox = m & 7;
  const int my = (m >> 3) * 2;                // 2*(m>>3)
  ushort_t tv[54];
  int j = 0;
#pragma unroll
  for (int ic2 = 0; ic2 < 2; ++ic2) {
    const int ic = sub * 2 + ic2;
#pragma unroll
    for (int dz = 0; dz < 3; ++dz) {
#pragma unroll
      for (int dy = 0; dy < 3; ++dy) {
        const int row = ic * 18 + dz * 6 + my + dy;
        const unsigned* rp = Hsd + row * 10;
        const unsigned d0 = (ox > 0) ? rp[ox - 1] : 0u;
        const unsigned d1 = rp[ox];
        tv[j]     = (ushort_t)(d0 >> 16);     // ix = 2ox-1
        tv[j + 1] = (ushort_t)(d1 & 0xFFFFu); // ix = 2ox
        tv[j + 2] = (ushort_t)(d1 >> 16);     // ix = 2ox+1
        j += 3;
      }
    }
  }
  __syncthreads();                            // Hs fully consumed

  // ---- write As (overwrites Hs region) + K-pad zeros ----
  {
    unsigned* Aw = (unsigned*)As;
    const int wbase = m * 228 + sub * 27;
#pragma unroll
    for (int p = 0; p < 27; ++p)
      Aw[wbase + p] = (unsigned)tv[2 * p] | ((unsigned)tv[2 * p + 1] << 16);
    Aw[(t >> 3) * 228 + 216 + (t & 7)] = 0u;  // k in [432,448)
  }
  __syncthreads();

  // ---- MFMA + store (bf16) ----
  f32x4 acc = {0.f, 0.f, 0.f, 0.f};
  const ushort_t* arow = &As[(l & 15) * 456 + ((l >> 4) << 3)];
#pragma unroll
  for (int kk = 0; kk < 14; ++kk) {
    const bf16x8 af = *(const bf16x8*)(const void*)&arow[kk * 32];
    acc = __builtin_amdgcn_mfma_f32_16x16x32_bf16(af, bfr[kk], acc, 0, 0, 0);
  }
  const int n = w * 16 + (l & 15);
  const int m0 = (l >> 4) << 2;
  ushort_t* cb = c2b + (((size_t)(bn * 32 + n) * 8) + oz) * 64 + yg * 16 + m0;
  const unsigned lo = (unsigned)f2bf(acc[0]) | ((unsigned)f2bf(acc[1]) << 16);
  const unsigned hi = (unsigned)f2bf(acc[2]) | ((unsigned)f2bf(acc[3]) << 16);
  *(uint2*)cb = make_uint2(lo, hi);
}

// ---------------- K2b: maxpool3 s2 p1 + bias + relu -> feat (bf16) ---------
// bf16 input (halved reads). Also zero-inits the 4 barrier states.
__global__ __launch_bounds__(256) void k_pool2(
    const ushort_t* __restrict__ c2b, const float* __restrict__ bc2,
    ushort_t* __restrict__ featb, int* __restrict__ bar)
{
  if (blockIdx.x == 0) {
    for (int i = threadIdx.x; i < 4096; i += 256) bar[i] = 0;
  }
  const int tid = blockIdx.x * 256 + threadIdx.x;  // 131072
  const int bn = tid >> 9, r = tid & 511;
  const int ch = r >> 4, pz = (r >> 2) & 3, py = r & 3;
  const ushort_t* base = c2b + ((size_t)(bn * 32 + ch) << 9);
  float m0 = -1e30f, m1 = -1e30f, m2 = -1e30f, m3 = -1e30f;
#pragma unroll
  for (int dz = 0; dz < 3; ++dz) {
    const int oz = 2 * pz - 1 + dz;
    if ((unsigned)oz >= 8u) continue;
#pragma unroll
    for (int dy = 0; dy < 3; ++dy) {
      const int oy = 2 * py - 1 + dy;
      if ((unsigned)oy >= 8u) continue;
      const uint4 v = *(const uint4*)(base + (oz << 6) + (oy << 3));
      const float x0 = __uint_as_float((v.x & 0xFFFFu) << 16);
      const float x1 = __uint_as_float(v.x & 0xFFFF0000u);
      const float x2 = __uint_as_float((v.y & 0xFFFFu) << 16);
      const float x3 = __uint_as_float(v.y & 0xFFFF0000u);
      const float x4 = __uint_as_float((v.z & 0xFFFFu) << 16);
      const float x5 = __uint_as_float(v.z & 0xFFFF0000u);
      const float x6 = __uint_as_float((v.w & 0xFFFFu) << 16);
      const float x7 = __uint_as_float(v.w & 0xFFFF0000u);
      m0 = fmaxf(m0, fmaxf(x0, x1));
      m1 = fmaxf(m1, fmaxf(x1, fmaxf(x2, x3)));
      m2 = fmaxf(m2, fmaxf(x3, fmaxf(x4, x5)));
      m3 = fmaxf(m3, fmaxf(x5, fmaxf(x6, x7)));
    }
  }
  const float bb = bc2[ch];
  const unsigned lo = (unsigned)f2bf(fmaxf(m0 + bb, 0.f)) |
                      ((unsigned)f2bf(fmaxf(m1 + bb, 0.f)) << 16);
  const unsigned hi = (unsigned)f2bf(fmaxf(m2 + bb, 0.f)) |
                      ((unsigned)f2bf(fmaxf(m3 + bb, 0.f)) << 16);
  *(uint2*)(featb + (size_t)bn * 2048 + r * 4) = make_uint2(lo, hi);
}

// ---------------- GCN layer body (X@W then A@P), used by k_tail ------------
// (R8 depth-2 prefetch form — measured neutral vs depth-1, kept.)
__device__ __forceinline__ void gcn_body(
    const ushort_t* __restrict__ Xb, const ushort_t* __restrict__ WT,
    const float* __restrict__ bias, const float* __restrict__ An,
    ushort_t* __restrict__ Ob, float* __restrict__ spw,
    int K, int N, int relu, int b, int jb,
    ushort_t (*As)[64 * 72], ushort_t (*Bs)[64 * 72], ushort_t* Ps)
{
  const int t = threadIdx.x, w = t >> 6, l = t & 63;
  const int r0 = t >> 3, kc0 = t & 7;
  const int lm = l & 15, lg = l >> 4;

  union { short s[8]; bf16x8 v; } afr[2];
  {
    const float* ap = An + b * 4096 + (16 * w + lm) * 64 + (lg << 3);
#pragma unroll
    for (int kc = 0; kc < 2; ++kc) {
      const float4 v0 = *(const float4*)(ap + kc * 32);
      const float4 v1 = *(const float4*)(ap + kc * 32 + 4);
      afr[kc].s[0] = (short)f2bf(v0.x); afr[kc].s[1] = (short)f2bf(v0.y);
      afr[kc].s[2] = (short)f2bf(v0.z); afr[kc].s[3] = (short)f2bf(v0.w);
      afr[kc].s[4] = (short)f2bf(v1.x); afr[kc].s[5] = (short)f2bf(v1.y);
      afr[kc].s[6] = (short)f2bf(v1.z); afr[kc].s[7] = (short)f2bf(v1.w);
    }
  }

  f32x4 acc[4];
#pragma unroll
  for (int nt = 0; nt < 4; ++nt) acc[nt] = (f32x4){0.f, 0.f, 0.f, 0.f};

  const ushort_t* arow0 = &Xb[(size_t)(b * 64 + r0) * K + kc0 * 8];
  const ushort_t* arow1 = &Xb[(size_t)(b * 64 + r0 + 32) * K + kc0 * 8];
  const ushort_t* brow0 = &WT[(size_t)(jb + r0) * K + kc0 * 8];
  const ushort_t* brow1 = &WT[(size_t)(jb + r0 + 32) * K + kc0 * 8];

  // prologue: set A holds kt=0, set B holds kt=64 (K >= 128 always)
  uint4 vaA0 = *(const uint4*)arow0;
  uint4 vaA1 = *(const uint4*)arow1;
  uint4 vbA0 = *(const uint4*)brow0;
  uint4 vbA1 = *(const uint4*)brow1;
  uint4 vaB0 = *(const uint4*)(arow0 + 64);
  uint4 vaB1 = *(const uint4*)(arow1 + 64);
  uint4 vbB0 = *(const uint4*)(brow0 + 64);
  uint4 vbB1 = *(const uint4*)(brow1 + 64);

  int buf = 0;
#pragma unroll 1
  for (int kt = 0; kt < K; kt += 128) {
    // ---- sub-iter A: data kt; prefetch kt+128 into set A ----
    *(uint4*)&As[buf][r0 * 72 + kc0 * 8]        = vaA0;
    *(uint4*)&As[buf][(r0 + 32) * 72 + kc0 * 8] = vaA1;
    *(uint4*)&Bs[buf][r0 * 72 + kc0 * 8]        = vbA0;
    *(uint4*)&Bs[buf][(r0 + 32) * 72 + kc0 * 8] = vbA1;
    __syncthreads();
    if (kt + 128 < K) {
      vaA0 = *(const uint4*)(arow0 + kt + 128);
      vaA1 = *(const uint4*)(arow1 + kt + 128);
      vbA0 = *(const uint4*)(brow0 + kt + 128);
      vbA1 = *(const uint4*)(brow1 + kt + 128);
    }
#pragma unroll
    for (int ks = 0; ks < 2; ++ks) {
      const bf16x8 af = *(const bf16x8*)(const void*)
          &As[buf][(16 * w + lm) * 72 + ks * 32 + (lg << 3)];
#pragma unroll
      for (int nt = 0; nt < 4; ++nt) {
        const bf16x8 bf = *(const bf16x8*)(const void*)
            &Bs[buf][(nt * 16 + lm) * 72 + ks * 32 + (lg << 3)];
        acc[nt] = __builtin_amdgcn_mfma_f32_16x16x32_bf16(af, bf, acc[nt], 0, 0, 0);
      }
    }
    buf ^= 1;
    // ---- sub-iter B: data kt+64; prefetch kt+192 into set B ----
    *(uint4*)&As[buf][r0 * 72 + kc0 * 8]        = vaB0;
    *(uint4*)&As[buf][(r0 + 32) * 72 + kc0 * 8] = vaB1;
    *(uint4*)&Bs[buf][r0 * 72 + kc0 * 8]        = vbB0;
    *(uint4*)&Bs[buf][(r0 + 32) * 72 + kc0 * 8] = vbB1;
    __syncthreads();
    if (kt + 192 < K) {
      vaB0 = *(const uint4*)(arow0 + kt + 192);
      vaB1 = *(const uint4*)(arow1 + kt + 192);
      vbB0 = *(const uint4*)(brow0 + kt + 192);
      vbB1 = *(const uint4*)(brow1 + kt + 192);
    }
#pragma unroll
    for (int ks = 0; ks < 2; ++ks) {
      const bf16x8 af = *(const bf16x8*)(const void*)
          &As[buf][(16 * w + lm) * 72 + ks * 32 + (lg << 3)];
#pragma unroll
      for (int nt = 0; nt < 4; ++nt) {
        const bf16x8 bf = *(const bf16x8*)(const void*)
            &Bs[buf][(nt * 16 + lm) * 72 + ks * 32 + (lg << 3)];
        acc[nt] = __builtin_amdgcn_mfma_f32_16x16x32_bf16(af, bf, acc[nt], 0, 0, 0);
      }
    }
    buf ^= 1;
  }

  __syncthreads();
  const int m0 = lg << 2;
#pragma unroll
  for (int nt = 0; nt < 4; ++nt) {
    const int n = nt * 16 + lm;
    const unsigned lo = (unsigned)f2bf(acc[nt][0]) | ((unsigned)f2bf(acc[nt][1]) << 16);
    const unsigned hi = (unsigned)f2bf(acc[nt][2]) | ((unsigned)f2bf(acc[nt][3]) << 16);
    *(uint2*)&Ps[n * 72 + 16 * w + m0] = make_uint2(lo, hi);
  }
  __syncthreads();

  float mx0 = -1e30f, mx1 = -1e30f, mx2 = -1e30f, mx3 = -1e30f;
#pragma unroll
  for (int nt = 0; nt < 4; ++nt) {
    const bf16x8 b0 = *(const bf16x8*)(const void*)&Ps[(nt * 16 + lm) * 72 + (lg << 3)];
    const bf16x8 b1 = *(const bf16x8*)(const void*)&Ps[(nt * 16 + lm) * 72 + 32 + (lg << 3)];
    f32x4 a2 = (f32x4){0.f, 0.f, 0.f, 0.f};
    a2 = __builtin_amdgcn_mfma_f32_16x16x32_bf16(afr[0].v, b0, a2, 0, 0, 0);
    a2 = __builtin_amdgcn_mfma_f32_16x16x32_bf16(afr[1].v, b1, a2, 0, 0, 0);
    const int col = jb + nt * 16 + lm;
    const float bv = bias[col];
    if (spw) {
      mx0 = fmaxf(mx0, a2[0] + bv);
      mx1 = fmaxf(mx1, a2[1] + bv);
      mx2 = fmaxf(mx2, a2[2] + bv);
      mx3 = fmaxf(mx3, a2[3] + bv);
    } else {
#pragma unroll
      for (int r = 0; r < 4; ++r) {
        const int row = b * 64 + 16 * w + m0 + r;
        float v = a2[r] + bv;
        if (relu) v = fmaxf(v, 0.f);
        Ob[(size_t)row * N + col] = f2bf(v);
      }
    }
  }
  if (spw) {
    // reduce over the 16 lm lanes (bits 0..3 of lane id); w/lg preserved
#pragma unroll
    for (int mk = 1; mk <= 8; mk <<= 1) {
      mx0 = fmaxf(mx0, __shfl_xor(mx0, mk));
      mx1 = fmaxf(mx1, __shfl_xor(mx1, mk));
      mx2 = fmaxf(mx2, __shfl_xor(mx2, mk));
      mx3 = fmaxf(mx3, __shfl_xor(mx3, mk));
    }
    if (lm == 0) {
      const int c = jb >> 6;
      const int n = 16 * w + m0;
      spw[b * 256 + (n + 0) * 4 + c] = mx0;
      spw[b * 256 + (n + 1) * 4 + c] = mx1;
      spw[b * 256 + (n + 2) * 4 + c] = mx2;
      spw[b * 256 + (n + 3) * 4 + c] = mx3;
    }
  }
}

// ---------------- fused tail: gcn1 | gcn2 | gcn3+chunkmax | fc1 | fc2 ------
// Plain launch, 64 blocks x 256 threads, 4 single-use grid barriers.
// Wait sets (arrive-only elsewhere): b0: blocks<32 (g1b readers);
// b1: blocks<16 (g2b readers); b2: all (spw readers); b3: blocks<4 (shw).
__global__ __launch_bounds__(256) void k_tail(
    const ushort_t* __restrict__ featb,
    const ushort_t* __restrict__ wg1T, const float* __restrict__ bg1,
    const ushort_t* __restrict__ wg2T, const float* __restrict__ bg2,
    const ushort_t* __restrict__ wg3T, const float* __restrict__ bg3,
    const float* __restrict__ An,
    ushort_t* __restrict__ g1b, ushort_t* __restrict__ g2b,
    float* __restrict__ spw, float* __restrict__ shw,
    const float* __restrict__ w1, const float* __restrict__ b1,
    const float* __restrict__ w2, const float* __restrict__ b2,
    float* __restrict__ out, int* __restrict__ bar)
{
  __shared__ ushort_t As[2][64 * 72];
  __shared__ ushort_t Bs[2][64 * 72];
  __shared__ ushort_t Ps[64 * 72];
  __shared__ float red[260];
  const int bx = blockIdx.x, t = threadIdx.x;

  // phase 1: gcn1  (all 64 blocks: 16 col-tiles x 4 graphs)
  gcn_body(featb, wg1T, bg1, An, g1b, nullptr, 2048, 1024, 1,
           bx >> 4, (bx & 15) << 6, As, Bs, Ps);
  gbar(bar, 0, 64, bx < 32);

  // phase 2: gcn2  (32 blocks: 8 col-tiles x 4 graphs)
  if (bx < 32)
    gcn_body(g1b, wg2T, bg2, An, g2b, nullptr, 1024, 512, 1,
             bx >> 3, (bx & 7) << 6, As, Bs, Ps);
  gbar(bar, 1, 64, bx < 16);

  // phase 3: gcn3 + fused 64-chunk max (16 blocks: 4 col-tiles x 4 graphs)
  if (bx < 16)
    gcn_body(g2b, wg3T, bg3, An, nullptr, spw, 512, 256, 0,
             bx >> 2, (bx & 3) << 6, As, Bs, Ps);
  gbar(bar, 2, 64, true);

  // phase 4: fc1 distributed: 2048 outputs over 64 blocks (32 each),
  // 8-way K-split per output + LDS reduce.
  {
    const int oo = t & 31, ks = t >> 5;          // ks in 0..7
    const int bb = bx >> 4;                      // graph
    const int jj = (bx & 15) * 32 + oo;          // fc1 column
    const float* spb = spw + bb * 256;
    float s = 0.f;
#pragma unroll
    for (int i = 0; i < 32; ++i) {
      const int k = ks * 32 + i;
      s += spb[k] * w1[k * 512 + jj];
    }
    red[t] = s;
    __syncthreads();
    if (t < 32) {
      float s2 = 0.f;
#pragma unroll
      for (int i = 0; i < 8; ++i) s2 += red[t + i * 32];
      const int j2 = (bx & 15) * 32 + t;
      shw[bb * 512 + j2] = fmaxf(s2 + b1[j2], 0.f);
    }
  }
  gbar(bar, 3, 64, bx < 4);

  // phase 5: fc2 + softmax (blocks 0..3, one per graph)
  if (bx < 4) {
    float s = 0.f;
    if (t < 128) {
      const int c = t & 3, ks2 = t >> 2;         // ks2 in 0..31
      const float* shb = shw + bx * 512;
#pragma unroll
      for (int i = 0; i < 16; ++i) {
        const int k = ks2 * 16 + i;
        s += shb[k] * w2[k * 4 + c];
      }
    }
    red[t] = s;
    __syncthreads();
    if (t < 4) {
      float s2 = b2[t];
#pragma unroll
      for (int i = 0; i < 32; ++i) s2 += red[t + i * 4];
      red[256 + t] = s2;
    }
    __syncthreads();
    if (t == 0) {
      const float a0 = red[256], a1 = red[257], a2v = red[258], a3 = red[259];
      const float mm = fmaxf(fmaxf(a0, a1), fmaxf(a2v, a3));
      const float e0 = expf(a0 - mm), e1 = expf(a1 - mm);
      const float e2 = expf(a2v - mm), e3 = expf(a3 - mm);
      const float inv = 1.f / (e0 + e1 + e2 + e3);
      out[bx * 4 + 0] = e0 * inv;
      out[bx * 4 + 1] = e1 * inv;
      out[bx * 4 + 2] = e2 * inv;
      out[bx * 4 + 3] = e3 * inv;
    }
  }
}

// ---------------------------------------------------------------------------
extern "C" void kernel_launch(void* const* d_in, const int* in_sizes, int n_in,
                              void* d_out, int out_size, void* d_ws, size_t ws_size,
                              hipStream_t stream)
{
  (void)in_sizes; (void)n_in; (void)out_size; (void)ws_size;
  const float* x   = (const float*)d_in[0];
  const int*   adj = (const int*)d_in[1];
  const float* wc1 = (const float*)d_in[3];
  const float* bc1 = (const float*)d_in[4];
  const float* wc2 = (const float*)d_in[5];
  const float* bc2 = (const float*)d_in[6];
  const float* wg1 = (const float*)d_in[7];
  const float* bg1 = (const float*)d_in[8];
  const float* wg2 = (const float*)d_in[9];
  const float* bg2 = (const float*)d_in[10];
  const float* wg3 = (const float*)d_in[11];
  const float* bg3 = (const float*)d_in[12];
  const float* wf1 = (const float*)d_in[13];
  const float* bf1 = (const float*)d_in[14];
  const float* wf2 = (const float*)d_in[15];
  const float* bf2 = (const float*)d_in[16];

  float* ws    = (float*)d_ws;
  ushort_t* h1 = (ushort_t*)d_ws;
  ushort_t* w2f   = (ushort_t*)(ws + 8388608);
  ushort_t* wg1Tb = (ushort_t*)(ws + 8395776);
  ushort_t* wg2Tb = (ushort_t*)(ws + 9444352);
  ushort_t* wg3Tb = (ushort_t*)(ws + 9706496);
  ushort_t* featb = (ushort_t*)(ws + 9772032);
  ushort_t* g1b   = (ushort_t*)(ws + 10034176);
  ushort_t* g2b   = (ushort_t*)(ws + 10165248);
  ushort_t* c2b  = (ushort_t*)(ws + 16777216);   // bf16; aliases xb16 region
  ushort_t* xb16 = (ushort_t*)(ws + 16777216);   // consumed pre-conv2
  float* An   = ws + 21495808;
  float* spw  = ws + 2621440;                    // in h1 region (dead after conv2)
  float* shw  = ws + 2622464;                    // in h1 region
  int*   bar  = (int*)(ws + 22364160);           // 4 x 1024-int barrier states
  float* outp = (float*)d_out;

  hipLaunchKernelGGL(k_prep,        dim3(10940),    dim3(256), 0, stream,
                     x, xb16, wc2, w2f, wg1, wg1Tb, wg2, wg2Tb, wg3, wg3Tb, adj, An);
  hipLaunchKernelGGL(k_conv1_mfma,  dim3(2048),     dim3(256), 0, stream, xb16, wc1, bc1, h1);
  hipLaunchKernelGGL(k_conv2,       dim3(8192),     dim3(128), 0, stream, h1, w2f, c2b);
  hipLaunchKernelGGL(k_pool2,       dim3(512),      dim3(256), 0, stream, c2b, bc2, featb, bar);
  hipLaunchKernelGGL(k_tail,        dim3(64),       dim3(256), 0, stream,
                     featb, wg1Tb, bg1, wg2Tb, bg2, wg3Tb, bg3, An, g1b, g2b,
                     spw, shw, wf1, bf1, wf2, bf2, outp, bar);
}

// Round 11
// 239.307 us; speedup vs baseline: 1.1398x; 1.0489x over previous
//
#include <hip/hip_runtime.h>

typedef unsigned short ushort_t;
typedef unsigned long long ull_t;
typedef __attribute__((ext_vector_type(8))) short bf16x8;
typedef __attribute__((ext_vector_type(4))) float f32x4;

static __device__ __forceinline__ unsigned short f2bf(float f) {
  unsigned u = __float_as_uint(f);
  u = (u + 0x7FFFu + ((u >> 16) & 1u)) >> 16;
  return (unsigned short)u;
}

static __device__ __forceinline__ uint4 pack8(const float4 a, const float4 b) {
  uint4 u;
  u.x = (unsigned)f2bf(a.x) | ((unsigned)f2bf(a.y) << 16);
  u.y = (unsigned)f2bf(a.z) | ((unsigned)f2bf(a.w) << 16);
  u.z = (unsigned)f2bf(b.x) | ((unsigned)f2bf(b.y) << 16);
  u.w = (unsigned)f2bf(b.z) | ((unsigned)f2bf(b.w) << 16);
  return u;
}

static __device__ __forceinline__ f32x4 max4(f32x4 a, f32x4 b) {
  f32x4 r;
  r[0] = fmaxf(a[0], b[0]); r[1] = fmaxf(a[1], b[1]);
  r[2] = fmaxf(a[2], b[2]); r[3] = fmaxf(a[3], b[3]);
  return r;
}

// Single-use hierarchical grid barrier (64 arrivals), per-barrier state.
// R7/R8: barrier design moves tail <2us; R9: >64 arrivals regresses.
// Layout per barrier: leaf[i]@i*32 (i<8), root@256, gen[i]@288+i*32.
static __device__ __forceinline__ void gbar(int* bar0, int bid, int nb,
                                            bool do_wait) {
  __syncthreads();
  if (threadIdx.x == 0) {
    int* bar = bar0 + (bid << 10);
    __threadfence();                        // release
    const int leaf = (blockIdx.x & 7) << 5;
    const int nleaf = nb >> 3;
    if (__hip_atomic_fetch_add(&bar[leaf], 1, __ATOMIC_ACQ_REL,
                               __HIP_MEMORY_SCOPE_AGENT) == nleaf - 1) {
      if (__hip_atomic_fetch_add(&bar[256], 1, __ATOMIC_ACQ_REL,
                                 __HIP_MEMORY_SCOPE_AGENT) == 7) {
#pragma unroll
        for (int i = 0; i < 8; ++i)
          __hip_atomic_store(&bar[288 + (i << 5)], 1, __ATOMIC_RELEASE,
                             __HIP_MEMORY_SCOPE_AGENT);
      }
    }
    if (do_wait) {
      int* mygen = &bar[288 + leaf];
      for (int it = 0; it < (1 << 22); ++it) {
        if (__hip_atomic_load(mygen, __ATOMIC_RELAXED,
                              __HIP_MEMORY_SCOPE_AGENT) != 0) break;
        __builtin_amdgcn_s_sleep(2);
      }
      __threadfence();                      // acquire
    }
  }
  __syncthreads();
}

// ---------------------------------------------------------------------------
// Workspace layout (fp32-element offsets):
//   h1    @ 0          : 16777216 ushorts (dead after conv2; spw/shw reuse it)
//     spw @ 2621440    : 1024 floats (chunk-max output)
//     shw @ 2622464    : 2048 floats (fc1 output)
//   w2f   @ 8388608    : 14336 ushorts (conv2 weight frags)
//   wg1Tb @ 8395776    : 1024x2048 ushorts
//   wg2Tb @ 9444352    : 512x1024 ushorts
//   wg3Tb @ 9706496    : 256x512 ushorts
//   featb @ 9772032    : 256x2048 ushorts
//   g1b   @ 10034176   : 256x1024 ushorts
//   g2b   @ 10165248   : 256x512 ushorts
//   c2b   @ 16777216   : 4194304 ushorts bf16 (xb16 ELIMINATED in R11)
//   An    @ 21495808   : 4*64*64
//   bar   @ 22364160   : 4096 ints (4 single-use barrier states x 1024)
// ---------------------------------------------------------------------------

__device__ __forceinline__ void prep_transpose(
    const float* __restrict__ W, ushort_t* __restrict__ out,
    int K, int N, int n0, int k0, int t, float (*tile)[33])
{
  const int tx = t & 31, ty = t >> 5;
#pragma unroll
  for (int i = 0; i < 4; ++i) {
    const int k = k0 + ty + i * 8;
    tile[ty + i * 8][tx] = W[(size_t)k * N + n0 + tx];
  }
  __syncthreads();
#pragma unroll
  for (int i = 0; i < 4; ++i) {
    const int n = n0 + ty + i * 8;
    out[(size_t)n * K + k0 + tx] = f2bf(tile[tx][ty + i * 8]);
  }
}

// ---------------- K1: fused prep+conv1 -------------------------------------
// Blocks 0..2047: conv1+maxpool3 MFMA "pooled-direct" (R8 form) with INLINE
// fp32->bf16 staging (bit-identical u0/u1/u2 to the old xb16 path; kills the
// 50MB xb16 round-trip). Blocks 2048..4795: prep's weight/An work — fully
// independent of conv1, runs concurrently in CU slots during ramp/drain.
__global__ __launch_bounds__(256) void k_pc1(
    const float* __restrict__ x, const float* __restrict__ wc,
    const float* __restrict__ bc, ushort_t* __restrict__ h1,
    const float* __restrict__ w2, ushort_t* __restrict__ w2f,
    const float* __restrict__ wg1, ushort_t* __restrict__ wg1T,
    const float* __restrict__ wg2, ushort_t* __restrict__ wg2T,
    const float* __restrict__ wg3, ushort_t* __restrict__ wg3T,
    const int* __restrict__ adj, float* __restrict__ An)
{
  __shared__ ushort_t L[2 * 34 * 76];
  __shared__ float tile[32][33];
  __shared__ float dinv[64];
  __shared__ int part[256];
  const int t = threadIdx.x;

  if (blockIdx.x >= 2048) {                  // ---- prep side ----
    int b = blockIdx.x - 2048;
    if (b < 56) {                            // conv2 weight frags
      const int tid = b * 256 + t;
      if (tid < 14336) {
        const int nt = tid / 7168, rem = tid % 7168;
        const int kk = rem / 512, rem2 = rem % 512;
        const int l = rem2 >> 3, j = rem2 & 7;
        const int n = nt * 16 + (l & 15);
        const int k = (l >> 4) * 8 + kk * 32 + j;
        float v = 0.f;
        if (k < 432) v = w2[n * 432 + k];
        w2f[tid] = f2bf(v);
      }
      return;
    }
    b -= 56;
    if (b < 2048) { prep_transpose(wg1, wg1T, 2048, 1024, (b & 31) << 5, (b >> 5) << 5, t, tile); return; }
    b -= 2048;
    if (b < 512)  { prep_transpose(wg2, wg2T, 1024, 512,  (b & 15) << 5, (b >> 4) << 5, t, tile); return; }
    b -= 512;
    if (b < 128)  { prep_transpose(wg3, wg3T, 512,  256,  (b & 7)  << 5, (b >> 3) << 5, t, tile); return; }
    b -= 128;
    {                                        // gcn_norm, b in [0,4)
      const int i = t >> 2, q = t & 3;
      const int* ab = adj + b * 4096 + i * 64 + q * 16;
      int d = 0;
#pragma unroll
      for (int j = 0; j < 16; ++j) d += (ab[j] != 0) ? 1 : 0;
      part[t] = d;
      __syncthreads();
      if (q == 0)
        dinv[i] = rsqrtf((float)(1 + part[t] + part[t + 1] + part[t + 2] + part[t + 3]));
      __syncthreads();
      for (int idx = t; idx < 4096; idx += 256) {
        const int ii = idx >> 6, jj = idx & 63;
        const float a = (ii == jj) ? 1.f : ((adj[b * 4096 + idx] != 0) ? 1.f : 0.f);
        An[b * 4096 + idx] = a * dinv[ii] * dinv[jj];
      }
    }
    return;
  }

  // ---- conv1 side (R8 form; only the staging loads changed to fp32) ----
  char* Lb = (char*)L;
  const int bn = blockIdx.x >> 3, zg = blockIdx.x & 7;
  const int w = t >> 6, l = t & 63;
  const int grp = l >> 4, m = l & 15, ch = l & 15;
  const float NINF = -1e30f;

  union { short s[8]; bf16x8 v; } uA, uB;
#pragma unroll
  for (int j = 0; j < 8; ++j) {
    const int k = grp * 8 + j;
    float wA = 0.f, wB = 0.f;
    if (k < 12) {
      const int dx = k >> 2, dz = k & 3;
      if (dz < 3) { wA = wc[ch*27 + dz*9 + 0 + dx]; wB = wc[ch*27 + dz*9 + 6 + dx]; }
    } else if (k >= 16 && k < 28) {
      const int kk = k - 16, dx = kk >> 2, dz = kk & 3;
      if (dz < 3) wA = wc[ch*27 + dz*9 + 3 + dx];
    }
    uA.s[j] = (short)f2bf(wA);
    uB.s[j] = (short)f2bf(wB);
  }

  int aX1[3], aX2[3];
#pragma unroll
  for (int s = 0; s < 3; ++s) {
    const int Q1 = 2*m + s + 2*(grp & 1);
    const int Q2 = Q1 + 1;
    aX1[s] = (Q1 & 1) * 5168 + (Q1 >> 1) * 8;
    aX2[s] = (Q2 & 1) * 5168 + (Q2 >> 1) * 8;
  }
  const int rsel = (grp >> 1) * 152;

  for (int u = t; u < 200; u += 256) {
    int addr;
    if (u < 72) {
      const int rr = (u < 36) ? 0 : 33;
      const int s = (u < 36) ? u : u - 36;
      const int pp = s / 18, slot = s - pp * 18;
      addr = pp * 5168 + rr * 152 + slot * 8;
    } else {
      const int v = u - 72;
      const int rr = 1 + (v >> 2);
      const int pp = (v >> 1) & 1;
      const int slot = (v & 1) * 17;
      addr = pp * 5168 + rr * 152 + slot * 8;
    }
    *(ull_t*)(Lb + addr) = 0ull;
  }

  f32x4 accZ[4][2];
#pragma unroll
  for (int j = 0; j < 4; ++j)
#pragma unroll
    for (int p = 0; p < 2; ++p) accZ[j][p] = (f32x4){NINF, NINF, NINF, NINF};

#pragma unroll 1
  for (int ci = 0; ci < 5; ++ci) {
    const int cz = 4*zg - 1 + ci;
    if (cz < 0) continue;
    if (t < 128) {
      const int r = 1 + (t >> 2), g = t & 3;
      const float* xrow = x + (size_t)bn * 32768 + (r - 1) * 32 + g * 8;
      uint4 u0 = make_uint4(0u, 0u, 0u, 0u), u2 = make_uint4(0u, 0u, 0u, 0u);
      uint4 u1;
      if (cz > 0) {
        const float4 a = *(const float4*)(xrow + (cz - 1) * 1024);
        const float4 c = *(const float4*)(xrow + (cz - 1) * 1024 + 4);
        u0 = pack8(a, c);
      }
      {
        const float4 a = *(const float4*)(xrow + cz * 1024);
        const float4 c = *(const float4*)(xrow + cz * 1024 + 4);
        u1 = pack8(a, c);
      }
      if (cz < 31) {
        const float4 a = *(const float4*)(xrow + (cz + 1) * 1024);
        const float4 c = *(const float4*)(xrow + (cz + 1) * 1024 + 4);
        u2 = pack8(a, c);
      }
      char* b0 = Lb + r * 152 + (4 * g + 1) * 8;
      char* b1 = Lb + 5168 + r * 152 + (4 * g + 1) * 8;
      const unsigned* p0 = (const unsigned*)&u0;
      const unsigned* p1 = (const unsigned*)&u1;
      const unsigned* p2 = (const unsigned*)&u2;
#pragma unroll
      for (int e = 0; e < 4; ++e) {
        const unsigned w0 = p0[e], w1 = p1[e], w2v = p2[e];
        const unsigned lo_e = (w0 & 0xFFFFu) | (w1 << 16);
        const unsigned hi_e = (w2v & 0xFFFFu);
        const unsigned lo_o = (w0 >> 16) | (w1 & 0xFFFF0000u);
        const unsigned hi_o = (w2v >> 16);
        *(ull_t*)(b0 + e * 8) = (ull_t)lo_e | ((ull_t)hi_e << 32);
        *(ull_t*)(b1 + e * 8) = (ull_t)lo_o | ((ull_t)hi_o << 32);
      }
    }
    __syncthreads();
    f32x4 accP0 = (f32x4){NINF, NINF, NINF, NINF};
    f32x4 accP1 = (f32x4){NINF, NINF, NINF, NINF};
#pragma unroll
    for (int yy = 0; yy < 9; ++yy) {
      if (yy == 0 && w == 0) continue;
      const int y = 8 * w - 1 + yy;
      const int rbA = y * 152 + rsel;
      const int rbB = (y + 2) * 152;
      f32x4 Cy;
#pragma unroll
      for (int s = 0; s < 3; ++s) {
        union { ull_t u[2]; bf16x8 v; } fA, fB;
        fA.u[0] = *(const ull_t*)(Lb + aX1[s] + rbA);
        fA.u[1] = *(const ull_t*)(Lb + aX2[s] + rbA);
        fB.u[0] = *(const ull_t*)(Lb + aX1[s] + rbB);
        fB.u[1] = *(const ull_t*)(Lb + aX2[s] + rbB);
        f32x4 acc = (f32x4){0.f, 0.f, 0.f, 0.f};
        acc = __builtin_amdgcn_mfma_f32_16x16x32_bf16(fA.v, uA.v, acc, 0, 0, 0);
        acc = __builtin_amdgcn_mfma_f32_16x16x32_bf16(fB.v, uB.v, acc, 0, 0, 0);
        if (s == 0) acc[0] = (l < 16) ? NINF : acc[0];
        Cy = (s == 0) ? acc : max4(Cy, acc);
      }
      if (yy & 1) {
        const int c = (yy - 1) / 2;
        if ((c & 1) == 0) accP0 = max4(accP0, Cy); else accP1 = max4(accP1, Cy);
      } else {
        const int cl = yy / 2 - 1;
        const int chh = yy / 2;
        if (cl >= 0) {
          if ((cl & 1) == 0) {
            accP0 = max4(accP0, Cy);
            if (ci <= 2) accZ[cl][0] = max4(accZ[cl][0], accP0);
            if (ci >= 2) accZ[cl][1] = max4(accZ[cl][1], accP0);
            accP0 = (f32x4){NINF, NINF, NINF, NINF};
          } else {
            accP1 = max4(accP1, Cy);
            if (ci <= 2) accZ[cl][0] = max4(accZ[cl][0], accP1);
            if (ci >= 2) accZ[cl][1] = max4(accZ[cl][1], accP1);
            accP1 = (f32x4){NINF, NINF, NINF, NINF};
          }
        }
        if (chh <= 3) {
          if ((chh & 1) == 0) accP0 = max4(accP0, Cy); else accP1 = max4(accP1, Cy);
        }
      }
    }
    __syncthreads();
  }

  const float biasv = bc[ch];
#pragma unroll
  for (int j = 0; j < 4; ++j) {
    const int py = 4 * w + j;
#pragma unroll
    for (int p = 0; p < 2; ++p) {
      const int pz = 2 * zg + p;
      const f32x4 v = accZ[j][p];
      const unsigned lo = (unsigned)f2bf(fmaxf(v[0] + biasv, 0.f)) |
                          ((unsigned)f2bf(fmaxf(v[1] + biasv, 0.f)) << 16);
      const unsigned hi = (unsigned)f2bf(fmaxf(v[2] + biasv, 0.f)) |
                          ((unsigned)f2bf(fmaxf(v[3] + biasv, 0.f)) << 16);
      ushort_t* dst = h1 + (((size_t)(bn * 16 + ch) * 16 + pz) << 8) + py * 16 + grp * 4;
      *(uint2*)dst = make_uint2(lo, hi);
    }
  }
}

// ---------------- K2: conv2 MFMA implicit GEMM, LDS-staged input -----------
// bf16 output (R9's orthogonal change, kept).
__global__ __launch_bounds__(128) void k_conv2(
    const ushort_t* __restrict__ h1, const ushort_t* __restrict__ w2f,
    ushort_t* __restrict__ c2b)
{
  __shared__ ushort_t U[16 * 456];            // 14592 B: Hs (11520 B) then As
  ushort_t* Hs = U;                           // Hs[row*20 + ix], row<288
  unsigned* Hsd = (unsigned*)U;               // dword view, stride 10
  ushort_t* As = U;                           // As[m*456 + k]
  const int b = blockIdx.x;
  const int bn = b >> 5, oz = (b >> 2) & 7, yg = b & 3;
  const int t = threadIdx.x;
  const ushort_t* hb = h1 + ((size_t)bn << 16);
  const int w = t >> 6, l = t & 63;

  bf16x8 bfr[14];
#pragma unroll
  for (int kk = 0; kk < 14; ++kk)
    bfr[kk] = *(const bf16x8*)(const void*)&w2f[(((w * 14) + kk) * 64 + l) * 8];

  // ---- stage Hs: 288 rows x 4 uint2-quads, coalesced, OOB -> 0 ----
#pragma unroll
  for (int it = 0; it < 9; ++it) {
    const int u = t + it * 128;               // 0..1151
    const int row = u >> 2, q = u & 3;
    const int ic = row / 18;
    const int r2 = row - ic * 18;
    const int izp = r2 / 6;
    const int iyp = r2 - izp * 6;
    const int iz = 2 * oz - 1 + izp;
    const int iy = 4 * yg - 1 + iyp;
    uint2 v = make_uint2(0u, 0u);
    if ((unsigned)iz < 16u && (unsigned)iy < 16u)
      v = *(const uint2*)(hb + (ic << 12) + (iz << 8) + (iy << 4) + q * 4);
    *(uint2*)&Hs[row * 20 + q * 4] = v;
  }
  __syncthreads();

  // ---- im2col gather from Hs into registers ----
  const int m = t >> 3, sub = t & 7;
  const int ox = m & 7;
  const int my = (m >> 3) * 2;                // 2*(m>>3)
  ushort_t tv[54];
  int j = 0;
#pragma unroll
  for (int ic2 = 0; ic2 < 2; ++ic2) {
    const int ic = sub * 2 + ic2;
#pragma unroll
    for (int dz = 0; dz < 3; ++dz) {
#pragma unroll
      for (int dy = 0; dy < 3; ++dy) {
        const int row = ic * 18 + dz * 6 + my + dy;
        const unsigned* rp = Hsd + row * 10;
        const unsigned d0 = (ox > 0) ? rp[ox - 1] : 0u;
        const unsigned d1 = rp[ox];
        tv[j]     = (ushort_t)(d0 >> 16);     // ix = 2ox-1
        tv[j + 1] = (ushort_t)(d1 & 0xFFFFu); // ix = 2ox
        tv[j + 2] = (ushort_t)(d1 >> 16);     // ix = 2ox+1
        j += 3;
      }
    }
  }
  __syncthreads();                            // Hs fully consumed

  // ---- write As (overwrites Hs region) + K-pad zeros ----
  {
    unsigned* Aw = (unsigned*)As;
    const int wbase = m * 228 + sub * 27;
#pragma unroll
    for (int p = 0; p < 27; ++p)
      Aw[wbase + p] = (unsigned)tv[2 * p] | ((unsigned)tv[2 * p + 1] << 16);
    Aw[(t >> 3) * 228 + 216 + (t & 7)] = 0u;  // k in [432,448)
  }
  __syncthreads();

  // ---- MFMA + store (bf16) ----
  f32x4 acc = {0.f, 0.f, 0.f, 0.f};
  const ushort_t* arow = &As[(l & 15) * 456 + ((l >> 4) << 3)];
#pragma unroll
  for (int kk = 0; kk < 14; ++kk) {
    const bf16x8 af = *(const bf16x8*)(const void*)&arow[kk * 32];
    acc = __builtin_amdgcn_mfma_f32_16x16x32_bf16(af, bfr[kk], acc, 0, 0, 0);
  }
  const int n = w * 16 + (l & 15);
  const int m0 = (l >> 4) << 2;
  ushort_t* cb = c2b + (((size_t)(bn * 32 + n) * 8) + oz) * 64 + yg * 16 + m0;
  const unsigned lo = (unsigned)f2bf(acc[0]) | ((unsigned)f2bf(acc[1]) << 16);
  const unsigned hi = (unsigned)f2bf(acc[2]) | ((unsigned)f2bf(acc[3]) << 16);
  *(uint2*)cb = make_uint2(lo, hi);
}

// ---------------- K2b: maxpool3 s2 p1 + bias + relu -> feat (bf16) ---------
// bf16 input. Also zero-inits the 4 barrier states for k_tail.
__global__ __launch_bounds__(256) void k_pool2(
    const ushort_t* __restrict__ c2b, const float* __restrict__ bc2,
    ushort_t* __restrict__ featb, int* __restrict__ bar)
{
  if (blockIdx.x == 0) {
    for (int i = threadIdx.x; i < 4096; i += 256) bar[i] = 0;
  }
  const int tid = blockIdx.x * 256 + threadIdx.x;  // 131072
  const int bn = tid >> 9, r = tid & 511;
  const int ch = r >> 4, pz = (r >> 2) & 3, py = r & 3;
  const ushort_t* base = c2b + ((size_t)(bn * 32 + ch) << 9);
  float m0 = -1e30f, m1 = -1e30f, m2 = -1e30f, m3 = -1e30f;
#pragma unroll
  for (int dz = 0; dz < 3; ++dz) {
    const int oz = 2 * pz - 1 + dz;
    if ((unsigned)oz >= 8u) continue;
#pragma unroll
    for (int dy = 0; dy < 3; ++dy) {
      const int oy = 2 * py - 1 + dy;
      if ((unsigned)oy >= 8u) continue;
      const uint4 v = *(const uint4*)(base + (oz << 6) + (oy << 3));
      const float x0 = __uint_as_float((v.x & 0xFFFFu) << 16);
      const float x1 = __uint_as_float(v.x & 0xFFFF0000u);
      const float x2 = __uint_as_float((v.y & 0xFFFFu) << 16);
      const float x3 = __uint_as_float(v.y & 0xFFFF0000u);
      const float x4 = __uint_as_float((v.z & 0xFFFFu) << 16);
      const float x5 = __uint_as_float(v.z & 0xFFFF0000u);
      const float x6 = __uint_as_float((v.w & 0xFFFFu) << 16);
      const float x7 = __uint_as_float(v.w & 0xFFFF0000u);
      m0 = fmaxf(m0, fmaxf(x0, x1));
      m1 = fmaxf(m1, fmaxf(x1, fmaxf(x2, x3)));
      m2 = fmaxf(m2, fmaxf(x3, fmaxf(x4, x5)));
      m3 = fmaxf(m3, fmaxf(x5, fmaxf(x6, x7)));
    }
  }
  const float bb = bc2[ch];
  const unsigned lo = (unsigned)f2bf(fmaxf(m0 + bb, 0.f)) |
                      ((unsigned)f2bf(fmaxf(m1 + bb, 0.f)) << 16);
  const unsigned hi = (unsigned)f2bf(fmaxf(m2 + bb, 0.f)) |
                      ((unsigned)f2bf(fmaxf(m3 + bb, 0.f)) << 16);
  *(uint2*)(featb + (size_t)bn * 2048 + r * 4) = make_uint2(lo, hi);
}

// ---------------- GCN layer body (X@W then A@P), used by k_tail ------------
// (R8 depth-2 prefetch form — measured neutral vs depth-1, kept.)
__device__ __forceinline__ void gcn_body(
    const ushort_t* __restrict__ Xb, const ushort_t* __restrict__ WT,
    const float* __restrict__ bias, const float* __restrict__ An,
    ushort_t* __restrict__ Ob, float* __restrict__ spw,
    int K, int N, int relu, int b, int jb,
    ushort_t (*As)[64 * 72], ushort_t (*Bs)[64 * 72], ushort_t* Ps)
{
  const int t = threadIdx.x, w = t >> 6, l = t & 63;
  const int r0 = t >> 3, kc0 = t & 7;
  const int lm = l & 15, lg = l >> 4;

  union { short s[8]; bf16x8 v; } afr[2];
  {
    const float* ap = An + b * 4096 + (16 * w + lm) * 64 + (lg << 3);
#pragma unroll
    for (int kc = 0; kc < 2; ++kc) {
      const float4 v0 = *(const float4*)(ap + kc * 32);
      const float4 v1 = *(const float4*)(ap + kc * 32 + 4);
      afr[kc].s[0] = (short)f2bf(v0.x); afr[kc].s[1] = (short)f2bf(v0.y);
      afr[kc].s[2] = (short)f2bf(v0.z); afr[kc].s[3] = (short)f2bf(v0.w);
      afr[kc].s[4] = (short)f2bf(v1.x); afr[kc].s[5] = (short)f2bf(v1.y);
      afr[kc].s[6] = (short)f2bf(v1.z); afr[kc].s[7] = (short)f2bf(v1.w);
    }
  }

  f32x4 acc[4];
#pragma unroll
  for (int nt = 0; nt < 4; ++nt) acc[nt] = (f32x4){0.f, 0.f, 0.f, 0.f};

  const ushort_t* arow0 = &Xb[(size_t)(b * 64 + r0) * K + kc0 * 8];
  const ushort_t* arow1 = &Xb[(size_t)(b * 64 + r0 + 32) * K + kc0 * 8];
  const ushort_t* brow0 = &WT[(size_t)(jb + r0) * K + kc0 * 8];
  const ushort_t* brow1 = &WT[(size_t)(jb + r0 + 32) * K + kc0 * 8];

  // prologue: set A holds kt=0, set B holds kt=64 (K >= 128 always)
  uint4 vaA0 = *(const uint4*)arow0;
  uint4 vaA1 = *(const uint4*)arow1;
  uint4 vbA0 = *(const uint4*)brow0;
  uint4 vbA1 = *(const uint4*)brow1;
  uint4 vaB0 = *(const uint4*)(arow0 + 64);
  uint4 vaB1 = *(const uint4*)(arow1 + 64);
  uint4 vbB0 = *(const uint4*)(brow0 + 64);
  uint4 vbB1 = *(const uint4*)(brow1 + 64);

  int buf = 0;
#pragma unroll 1
  for (int kt = 0; kt < K; kt += 128) {
    // ---- sub-iter A: data kt; prefetch kt+128 into set A ----
    *(uint4*)&As[buf][r0 * 72 + kc0 * 8]        = vaA0;
    *(uint4*)&As[buf][(r0 + 32) * 72 + kc0 * 8] = vaA1;
    *(uint4*)&Bs[buf][r0 * 72 + kc0 * 8]        = vbA0;
    *(uint4*)&Bs[buf][(r0 + 32) * 72 + kc0 * 8] = vbA1;
    __syncthreads();
    if (kt + 128 < K) {
      vaA0 = *(const uint4*)(arow0 + kt + 128);
      vaA1 = *(const uint4*)(arow1 + kt + 128);
      vbA0 = *(const uint4*)(brow0 + kt + 128);
      vbA1 = *(const uint4*)(brow1 + kt + 128);
    }
#pragma unroll
    for (int ks = 0; ks < 2; ++ks) {
      const bf16x8 af = *(const bf16x8*)(const void*)
          &As[buf][(16 * w + lm) * 72 + ks * 32 + (lg << 3)];
#pragma unroll
      for (int nt = 0; nt < 4; ++nt) {
        const bf16x8 bf = *(const bf16x8*)(const void*)
            &Bs[buf][(nt * 16 + lm) * 72 + ks * 32 + (lg << 3)];
        acc[nt] = __builtin_amdgcn_mfma_f32_16x16x32_bf16(af, bf, acc[nt], 0, 0, 0);
      }
    }
    buf ^= 1;
    // ---- sub-iter B: data kt+64; prefetch kt+192 into set B ----
    *(uint4*)&As[buf][r0 * 72 + kc0 * 8]        = vaB0;
    *(uint4*)&As[buf][(r0 + 32) * 72 + kc0 * 8] = vaB1;
    *(uint4*)&Bs[buf][r0 * 72 + kc0 * 8]        = vbB0;
    *(uint4*)&Bs[buf][(r0 + 32) * 72 + kc0 * 8] = vbB1;
    __syncthreads();
    if (kt + 192 < K) {
      vaB0 = *(const uint4*)(arow0 + kt + 192);
      vaB1 = *(const uint4*)(arow1 + kt + 192);
      vbB0 = *(const uint4*)(brow0 + kt + 192);
      vbB1 = *(const uint4*)(brow1 + kt + 192);
    }
#pragma unroll
    for (int ks = 0; ks < 2; ++ks) {
      const bf16x8 af = *(const bf16x8*)(const void*)
          &As[buf][(16 * w + lm) * 72 + ks * 32 + (lg << 3)];
#pragma unroll
      for (int nt = 0; nt < 4; ++nt) {
        const bf16x8 bf = *(const bf16x8*)(const void*)
            &Bs[buf][(nt * 16 + lm) * 72 + ks * 32 + (lg << 3)];
        acc[nt] = __builtin_amdgcn_mfma_f32_16x16x32_bf16(af, bf, acc[nt], 0, 0, 0);
      }
    }
    buf ^= 1;
  }

  __syncthreads();
  const int m0 = lg << 2;
#pragma unroll
  for (int nt = 0; nt < 4; ++nt) {
    const int n = nt * 16 + lm;
    const unsigned lo = (unsigned)f2bf(acc[nt][0]) | ((unsigned)f2bf(acc[nt][1]) << 16);
    const unsigned hi = (unsigned)f2bf(acc[nt][2]) | ((unsigned)f2bf(acc[nt][3]) << 16);
    *(uint2*)&Ps[n * 72 + 16 * w + m0] = make_uint2(lo, hi);
  }
  __syncthreads();

  float mx0 = -1e30f, mx1 = -1e30f, mx2 = -1e30f, mx3 = -1e30f;
#pragma unroll
  for (int nt = 0; nt < 4; ++nt) {
    const bf16x8 b0 = *(const bf16x8*)(const void*)&Ps[(nt * 16 + lm) * 72 + (lg << 3)];
    const bf16x8 b1 = *(const bf16x8*)(const void*)&Ps[(nt * 16 + lm) * 72 + 32 + (lg << 3)];
    f32x4 a2 = (f32x4){0.f, 0.f, 0.f, 0.f};
    a2 = __builtin_amdgcn_mfma_f32_16x16x32_bf16(afr[0].v, b0, a2, 0, 0, 0);
    a2 = __builtin_amdgcn_mfma_f32_16x16x32_bf16(afr[1].v, b1, a2, 0, 0, 0);
    const int col = jb + nt * 16 + lm;
    const float bv = bias[col];
    if (spw) {
      mx0 = fmaxf(mx0, a2[0] + bv);
      mx1 = fmaxf(mx1, a2[1] + bv);
      mx2 = fmaxf(mx2, a2[2] + bv);
      mx3 = fmaxf(mx3, a2[3] + bv);
    } else {
#pragma unroll
      for (int r = 0; r < 4; ++r) {
        const int row = b * 64 + 16 * w + m0 + r;
        float v = a2[r] + bv;
        if (relu) v = fmaxf(v, 0.f);
        Ob[(size_t)row * N + col] = f2bf(v);
      }
    }
  }
  if (spw) {
    // reduce over the 16 lm lanes (bits 0..3 of lane id); w/lg preserved
#pragma unroll
    for (int mk = 1; mk <= 8; mk <<= 1) {
      mx0 = fmaxf(mx0, __shfl_xor(mx0, mk));
      mx1 = fmaxf(mx1, __shfl_xor(mx1, mk));
      mx2 = fmaxf(mx2, __shfl_xor(mx2, mk));
      mx3 = fmaxf(mx3, __shfl_xor(mx3, mk));
    }
    if (lm == 0) {
      const int c = jb >> 6;
      const int n = 16 * w + m0;
      spw[b * 256 + (n + 0) * 4 + c] = mx0;
      spw[b * 256 + (n + 1) * 4 + c] = mx1;
      spw[b * 256 + (n + 2) * 4 + c] = mx2;
      spw[b * 256 + (n + 3) * 4 + c] = mx3;
    }
  }
}

// ---------------- fused tail: gcn1 | gcn2 | gcn3+chunkmax | fc1 | fc2 ------
// Plain launch, 64 blocks x 256 threads, 4 single-use grid barriers.
__global__ __launch_bounds__(256) void k_tail(
    const ushort_t* __restrict__ featb,
    const ushort_t* __restrict__ wg1T, const float* __restrict__ bg1,
    const ushort_t* __restrict__ wg2T, const float* __restrict__ bg2,
    const ushort_t* __restrict__ wg3T, const float* __restrict__ bg3,
    const float* __restrict__ An,
    ushort_t* __restrict__ g1b, ushort_t* __restrict__ g2b,
    float* __restrict__ spw, float* __restrict__ shw,
    const float* __restrict__ w1, const float* __restrict__ b1,
    const float* __restrict__ w2, const float* __restrict__ b2,
    float* __restrict__ out, int* __restrict__ bar)
{
  __shared__ ushort_t As[2][64 * 72];
  __shared__ ushort_t Bs[2][64 * 72];
  __shared__ ushort_t Ps[64 * 72];
  __shared__ float red[260];
  const int bx = blockIdx.x, t = threadIdx.x;

  // phase 1: gcn1  (all 64 blocks: 16 col-tiles x 4 graphs)
  gcn_body(featb, wg1T, bg1, An, g1b, nullptr, 2048, 1024, 1,
           bx >> 4, (bx & 15) << 6, As, Bs, Ps);
  gbar(bar, 0, 64, bx < 32);

  // phase 2: gcn2  (32 blocks: 8 col-tiles x 4 graphs)
  if (bx < 32)
    gcn_body(g1b, wg2T, bg2, An, g2b, nullptr, 1024, 512, 1,
             bx >> 3, (bx & 7) << 6, As, Bs, Ps);
  gbar(bar, 1, 64, bx < 16);

  // phase 3: gcn3 + fused 64-chunk max (16 blocks: 4 col-tiles x 4 graphs)
  if (bx < 16)
    gcn_body(g2b, wg3T, bg3, An, nullptr, spw, 512, 256, 0,
             bx >> 2, (bx & 3) << 6, As, Bs, Ps);
  gbar(bar, 2, 64, true);

  // phase 4: fc1 distributed: 2048 outputs over 64 blocks (32 each),
  // 8-way K-split per output + LDS reduce.
  {
    const int oo = t & 31, ks = t >> 5;          // ks in 0..7
    const int bb = bx >> 4;                      // graph
    const int jj = (bx & 15) * 32 + oo;          // fc1 column
    const float* spb = spw + bb * 256;
    float s = 0.f;
#pragma unroll
    for (int i = 0; i < 32; ++i) {
      const int k = ks * 32 + i;
      s += spb[k] * w1[k * 512 + jj];
    }
    red[t] = s;
    __syncthreads();
    if (t < 32) {
      float s2 = 0.f;
#pragma unroll
      for (int i = 0; i < 8; ++i) s2 += red[t + i * 32];
      const int j2 = (bx & 15) * 32 + t;
      shw[bb * 512 + j2] = fmaxf(s2 + b1[j2], 0.f);
    }
  }
  gbar(bar, 3, 64, bx < 4);

  // phase 5: fc2 + softmax (blocks 0..3, one per graph)
  if (bx < 4) {
    float s = 0.f;
    if (t < 128) {
      const int c = t & 3, ks2 = t >> 2;         // ks2 in 0..31
      const float* shb = shw + bx * 512;
#pragma unroll
      for (int i = 0; i < 16; ++i) {
        const int k = ks2 * 16 + i;
        s += shb[k] * w2[k * 4 + c];
      }
    }
    red[t] = s;
    __syncthreads();
    if (t < 4) {
      float s2 = b2[t];
#pragma unroll
      for (int i = 0; i < 32; ++i) s2 += red[t + i * 4];
      red[256 + t] = s2;
    }
    __syncthreads();
    if (t == 0) {
      const float a0 = red[256], a1 = red[257], a2v = red[258], a3 = red[259];
      const float mm = fmaxf(fmaxf(a0, a1), fmaxf(a2v, a3));
      const float e0 = expf(a0 - mm), e1 = expf(a1 - mm);
      const float e2 = expf(a2v - mm), e3 = expf(a3 - mm);
      const float inv = 1.f / (e0 + e1 + e2 + e3);
      out[bx * 4 + 0] = e0 * inv;
      out[bx * 4 + 1] = e1 * inv;
      out[bx * 4 + 2] = e2 * inv;
      out[bx * 4 + 3] = e3 * inv;
    }
  }
}

// ---------------------------------------------------------------------------
extern "C" void kernel_launch(void* const* d_in, const int* in_sizes, int n_in,
                              void* d_out, int out_size, void* d_ws, size_t ws_size,
                              hipStream_t stream)
{
  (void)in_sizes; (void)n_in; (void)out_size; (void)ws_size;
  const float* x   = (const float*)d_in[0];
  const int*   adj = (const int*)d_in[1];
  const float* wc1 = (const float*)d_in[3];
  const float* bc1 = (const float*)d_in[4];
  const float* wc2 = (const float*)d_in[5];
  const float* bc2 = (const float*)d_in[6];
  const float* wg1 = (const float*)d_in[7];
  const float* bg1 = (const float*)d_in[8];
  const float* wg2 = (const float*)d_in[9];
  const float* bg2 = (const float*)d_in[10];
  const float* wg3 = (const float*)d_in[11];
  const float* bg3 = (const float*)d_in[12];
  const float* wf1 = (const float*)d_in[13];
  const float* bf1 = (const float*)d_in[14];
  const float* wf2 = (const float*)d_in[15];
  const float* bf2 = (const float*)d_in[16];

  float* ws    = (float*)d_ws;
  ushort_t* h1 = (ushort_t*)d_ws;
  ushort_t* w2f   = (ushort_t*)(ws + 8388608);
  ushort_t* wg1Tb = (ushort_t*)(ws + 8395776);
  ushort_t* wg2Tb = (ushort_t*)(ws + 9444352);
  ushort_t* wg3Tb = (ushort_t*)(ws + 9706496);
  ushort_t* featb = (ushort_t*)(ws + 9772032);
  ushort_t* g1b   = (ushort_t*)(ws + 10034176);
  ushort_t* g2b   = (ushort_t*)(ws + 10165248);
  ushort_t* c2b  = (ushort_t*)(ws + 16777216);   // bf16 conv2 out
  float* An   = ws + 21495808;
  float* spw  = ws + 2621440;                    // in h1 region (dead after conv2)
  float* shw  = ws + 2622464;                    // in h1 region
  int*   bar  = (int*)(ws + 22364160);           // 4 x 1024-int barrier states
  float* outp = (float*)d_out;

  hipLaunchKernelGGL(k_pc1,   dim3(4796), dim3(256), 0, stream,
                     x, wc1, bc1, h1, wc2, w2f, wg1, wg1Tb, wg2, wg2Tb,
                     wg3, wg3Tb, adj, An);
  hipLaunchKernelGGL(k_conv2, dim3(8192), dim3(128), 0, stream, h1, w2f, c2b);
  hipLaunchKernelGGL(k_pool2, dim3(512),  dim3(256), 0, stream, c2b, bc2, featb, bar);
  hipLaunchKernelGGL(k_tail,  dim3(64),   dim3(256), 0, stream,
                     featb, wg1Tb, bg1, wg2Tb, bg2, wg3Tb, bg3, An, g1b, g2b,
                     spw, shw, wf1, bf1, wf2, bf2, outp, bar);
}